// Round 2
// 891.492 us; speedup vs baseline: 1.1578x; 1.1578x over previous
//
#include <hip/hip_runtime.h>
#include <stdint.h>

#define HH 200
#define WW 200
#define HWSZ 40000
#define NPX 80000

typedef __attribute__((ext_vector_type(8))) short bf16x8;
typedef __attribute__((ext_vector_type(4))) float f32x4;

__device__ __forceinline__ float bf2f(unsigned short u) {
    union { uint32_t i; float f; } c; c.i = ((uint32_t)u) << 16; return c.f;
}
__device__ __forceinline__ unsigned short f2bf(float f) {
    union { float f; uint32_t i; } c; c.f = f;
    uint32_t r = c.i + 0x7FFF + ((c.i >> 16) & 1);   // RNE
    return (unsigned short)(r >> 16);
}
__device__ __forceinline__ unsigned int cvtpk_bf16(float lo, float hi) {
    unsigned int r;
    asm("v_cvt_pk_bf16_f32 %0, %1, %2" : "=v"(r) : "v"(lo), "v"(hi));
    return r;
}

// ---------------------------------------------------------------------------
// Weight conversion: fp32 -> bf16; W1/W2 transposed to [cout][cin];
// Wcat = concat(Wo, Wr) along k (k<256 -> Wo, k>=256 -> Wr).
// ---------------------------------------------------------------------------
__global__ __launch_bounds__(256) void cvt_weights(
    const float* __restrict__ Wq, const float* __restrict__ Wk,
    const float* __restrict__ Wv, const float* __restrict__ Wo,
    const float* __restrict__ Wr, const float* __restrict__ W1,
    const float* __restrict__ W2,
    unsigned short* Wq_b, unsigned short* Wk_b, unsigned short* Wv_b,
    unsigned short* Wcat, unsigned short* W1t, unsigned short* W2t)
{
    const int seg = blockIdx.y;
    const int idx = blockIdx.x * 256 + threadIdx.x;
    if (seg == 0)      { if (idx < 16384) Wq_b[idx] = f2bf(Wq[idx]); }
    else if (seg == 1) { if (idx < 65536) Wk_b[idx] = f2bf(Wk[idx]); }
    else if (seg == 2) { if (idx < 65536) Wv_b[idx] = f2bf(Wv[idx]); }
    else if (seg == 3) {
        if (idx < 81920) {
            int r = idx / 320, k = idx - r * 320;
            Wcat[idx] = f2bf(k < 256 ? Wo[r * 256 + k] : Wr[r * 64 + (k - 256)]);
        }
    } else if (seg == 4) {
        if (idx < 262144) { int o = idx >> 8, i = idx & 255; W1t[idx] = f2bf(W1[i * 1024 + o]); }
    } else {
        if (idx < 262144) { int o = idx >> 10, i = idx & 1023; W2t[idx] = f2bf(W2[i * 256 + o]); }
    }
}

// ---------------------------------------------------------------------------
// NCHW fp32 -> NHWC bf16 (64px x 64c LDS tile).
// ---------------------------------------------------------------------------
__global__ __launch_bounds__(256) void to_nhwc(
    const float* __restrict__ src, unsigned short* __restrict__ dst, int C)
{
    __shared__ unsigned short T[64][72];
    const int b = blockIdx.z, c0 = blockIdx.y * 64, px0 = blockIdx.x * 64;
    const int t = threadIdx.x;
    const int pxl = t & 63, cl0 = t >> 6;
    const float* sp = src + ((size_t)(b * C + c0 + cl0)) * HWSZ + px0 + pxl;
    #pragma unroll
    for (int i = 0; i < 16; ++i)
        T[pxl][cl0 + i * 4] = f2bf(sp[(size_t)i * 4 * HWSZ]);
    __syncthreads();
    #pragma unroll
    for (int r = 0; r < 2; ++r) {
        int idx = t + r * 256;
        int p = idx >> 3, cof = (idx & 7) * 8;
        uint4 v = *(const uint4*)&T[p][cof];
        *(uint4*)(dst + ((size_t)(b * HWSZ + px0 + p)) * C + c0 + cof) = v;
    }
}

// ---------------------------------------------------------------------------
// bf16 MFMA GEMM (NHWC activations x row-major [cout][cin] weights).
// Out[px][cout] = sum_k In[px][k] * W[cout][k]; M=80000, tile 128x128, BK=32.
// Optional concat second input (k >= K1 -> In2). Out: bf16 (OutB) or fp32
// (OutF). flags: 1=relu, 2=fp32 accumulate. Out row stride fixed at 256.
// ---------------------------------------------------------------------------
__global__ __launch_bounds__(256) void gemm_bf16(
    const unsigned short* __restrict__ In, int inStride,
    const unsigned short* __restrict__ In2, int in2Stride, int K1,
    const unsigned short* __restrict__ Wb, int wStride, int Ktot,
    unsigned short* __restrict__ OutB, float* __restrict__ OutF,
    const float* __restrict__ bias, int flags)
{
    __shared__ bf16x8 AB[1024];   // [0..511] A frags, [512..1023] B frags
    const int t = threadIdx.x;
    const int px0 = blockIdx.x * 128;
    const int n0 = blockIdx.y * 128;
    const int lane = t & 63, w = t >> 6;
    const int mh = w & 1, nh = w >> 1;

    f32x4 acc[4][4] = {};

    for (int k0 = 0; k0 < Ktot; k0 += 32) {
        #pragma unroll
        for (int r = 0; r < 2; ++r) {
            const int c = t + r * 256;
            const int l = c & 63;
            const int ko = k0 + ((l >> 4) << 3);
            {
                const int mt = c >> 6;
                const int px = px0 + mt * 16 + (l & 15);
                const unsigned short* sp = (ko < K1)
                    ? (In  + (size_t)px * inStride  + ko)
                    : (In2 + (size_t)px * in2Stride + (ko - K1));
                AB[c] = *(const bf16x8*)sp;
            }
            {
                const int nt = c >> 6;
                const int cc = n0 + nt * 16 + (l & 15);
                AB[512 + c] = *(const bf16x8*)(Wb + (size_t)cc * wStride + ko);
            }
        }
        __syncthreads();
        bf16x8 av[4], bv[4];
        #pragma unroll
        for (int i = 0; i < 4; ++i) av[i] = AB[(mh * 4 + i) * 64 + lane];
        #pragma unroll
        for (int j = 0; j < 4; ++j) bv[j] = AB[512 + (nh * 4 + j) * 64 + lane];
        #pragma unroll
        for (int i = 0; i < 4; ++i)
            #pragma unroll
            for (int j = 0; j < 4; ++j)
                acc[i][j] = __builtin_amdgcn_mfma_f32_16x16x32_bf16(
                    av[i], bv[j], acc[i][j], 0, 0, 0);
        __syncthreads();
    }

    const int q = lane >> 4, ln = lane & 15;
    const bool relu = (flags & 1) != 0, accum = (flags & 2) != 0;
    #pragma unroll
    for (int i = 0; i < 4; ++i) {
        #pragma unroll
        for (int j = 0; j < 4; ++j) {
            const int coutv = n0 + nh * 64 + j * 16 + ln;
            const float bval = bias ? bias[coutv] : 0.0f;
            #pragma unroll
            for (int r = 0; r < 4; ++r) {
                const int px = px0 + mh * 64 + i * 16 + q * 4 + r;
                float v = acc[i][j][r] + bval;
                if (relu) v = fmaxf(v, 0.0f);
                if (OutB) {
                    OutB[(size_t)px * 256 + coutv] = f2bf(v);
                } else {
                    float* op = OutF + (size_t)px * 256 + coutv;
                    if (accum) v += *op;
                    *op = v;
                }
            }
        }
    }
}

// ---------------------------------------------------------------------------
// 7x7 local-window attention via MFMA, NHWC bf16, replicate pad via clamp.
// Block = (b, head, 16x16 px tile), 4 waves, wave handles 4 pixel-rows.
// Per row h, tap-row i: swapped QK^T  S[kcol][w] = sum_c K[kcol][c]*Q[w][c]
// as 2x mfma_16x16x32 (kcol halves as M, 16 pixels as N, 32ch as K).
// Lane (g,n) reg r holds S[kcol=4g+r(/+16)][pixel n] -> softmax with only a
// 4-lane shfl_xor(16/32) reduce. P -> bf16 via v_cvt_pk_bf16_f32, then
// redistributed to A-frag order: dest lane (g',n) word0/1 come from source
// lane (2*(g'&1), n), word2/3 from (2*(g'&1)+1, n); pa/pb (kcol<16) vs pc/pd
// (kcol>=16) is selected at the DESTINATION (shuffle both, cndmask by g'>=2)
// -- selecting inside the shfl would use the SOURCE lane's predicate (the
// round-1 bug). P is exactly 0 for kcol>=22 (exp masked), V pads finite.
// PV = mfma(P', Vt) accumulated over the 7 tap-rows.
// K,Q frags read directly from global (contiguous in c, L1/L2-resident).
// V staged once per block into transposed LDS vt[ch][r][c]:
//   ch-stride 536 hw (1072 B, 16B-aligned), row stride 24 hw; pad cols 22/23
//   + 8-hw tail zeroed so every b128 read (incl. g=3 overrun into next row /
//   tail) sees finite data.
// ---------------------------------------------------------------------------
__global__ __launch_bounds__(256) void attn_bf16(
    const unsigned short* Q, const unsigned short* __restrict__ K,
    const unsigned short* __restrict__ V, unsigned short* A)
{
    __shared__ __align__(16) unsigned short vt[32 * 536];   // 34304 B
    const int b = blockIdx.z, head = blockIdx.y;
    const int tiy = blockIdx.x / 13, tix = blockIdx.x % 13;
    const int h0 = tiy * 16, w0 = tix * 16;
    const int t = threadIdx.x;
    const int lane = t & 63, wv = t >> 6;
    const int g = lane >> 4, n = lane & 15;
    const int co = head * 32;
    const size_t pxb = (size_t)b * HWSZ;

    // zero the pad regions (cols 22,23 of each (ch,r) row + 8-hw tail per ch)
    for (int idx = t; idx < 832; idx += 256) {
        if (idx < 704) {
            int ch = idx / 22, r = idx - ch * 22;
            *(unsigned int*)&vt[ch * 536 + r * 24 + 22] = 0u;
        } else {
            int k2 = idx - 704;
            int ch = k2 >> 2, e = k2 & 3;
            *(unsigned int*)&vt[ch * 536 + 528 + e * 2] = 0u;
        }
    }
    // stage V halo, transposed
    for (int idx = t; idx < 484 * 4; idx += 256) {
        int pos = idx >> 2, chunk = idx & 3;
        int r = pos / 22, c = pos - r * 22;
        int gh = min(max(h0 + r - 3, 0), HH - 1);
        int gw = min(max(w0 + c - 3, 0), WW - 1);
        bf16x8 v8 = *(const bf16x8*)(V + (pxb + gh * WW + gw) * 256 + co + chunk * 8);
        unsigned short* dp = &vt[(chunk * 8) * 536 + r * 24 + c];
        #pragma unroll
        for (int e = 0; e < 8; ++e) dp[e * 536] = (unsigned short)v8[e];
    }
    __syncthreads();

    const f32x4 z4 = {0.f, 0.f, 0.f, 0.f};
    const int qw  = min(w0 + n, WW - 1);
    const int kc0 = min(max(w0 - 3 + n, 0), WW - 1);   // halo col n
    const int kc1 = min(w0 + 13 + n, WW - 1);          // halo col n + 16
    const bool hi2 = (g >> 1) != 0;
    const int src0 = ((g & 1) * 2) * 16 + n;
    const int src1 = src0 + 16;

    for (int hh = 0; hh < 4; ++hh) {
        const int hl = wv * 4 + hh;
        const int h = h0 + hl;
        const int hc = min(h, HH - 1);

        // Q fragment (B operand): lane (g,n) = Q[pixel w0+n][co + g*8 ..]
        const bf16x8 qf = *(const bf16x8*)(Q + (pxb + hc * WW + qw) * 256 + co + g * 8);

        // QK^T: S[kcol][w], kcol halves 0-15 / 16-31
        f32x4 s0[7], s1[7];
        #pragma unroll
        for (int i = 0; i < 7; ++i) {
            const int gh = min(max(h - 3 + i, 0), HH - 1);
            const unsigned short* kr = K + (pxb + gh * WW) * 256 + co + g * 8;
            bf16x8 a0 = *(const bf16x8*)(kr + (size_t)kc0 * 256);
            bf16x8 a1 = *(const bf16x8*)(kr + (size_t)kc1 * 256);
            s0[i] = __builtin_amdgcn_mfma_f32_16x16x32_bf16(a0, qf, z4, 0, 0, 0);
            s1[i] = __builtin_amdgcn_mfma_f32_16x16x32_bf16(a1, qf, z4, 0, 0, 0);
        }

        // softmax over the 49 window taps of pixel n: valid kcol in [n, n+6]
        float mx = -3.0e38f;
        #pragma unroll
        for (int r = 0; r < 4; ++r) {
            float m0 = s0[0][r], m1 = s1[0][r];
            #pragma unroll
            for (int i = 1; i < 7; ++i) {
                m0 = fmaxf(m0, s0[i][r]);
                m1 = fmaxf(m1, s1[i][r]);
            }
            const int k0 = 4 * g + r, k1 = k0 + 16;
            mx = fmaxf(mx, ((unsigned)(k0 - n) <= 6u) ? m0 : -3.0e38f);
            mx = fmaxf(mx, ((unsigned)(k1 - n) <= 6u) ? m1 : -3.0e38f);
        }
        mx = fmaxf(mx, __shfl_xor(mx, 16));
        mx = fmaxf(mx, __shfl_xor(mx, 32));

        float sum = 0.0f;
        #pragma unroll
        for (int r = 0; r < 4; ++r) {
            const int k0 = 4 * g + r, k1 = k0 + 16;
            const bool in0 = (unsigned)(k0 - n) <= 6u;
            const bool in1 = (unsigned)(k1 - n) <= 6u;
            #pragma unroll
            for (int i = 0; i < 7; ++i) {
                float e0 = in0 ? __expf((s0[i][r] - mx) * 0.17677669529663687f) : 0.0f;
                float e1 = in1 ? __expf((s1[i][r] - mx) * 0.17677669529663687f) : 0.0f;
                s0[i][r] = e0; s1[i][r] = e1;
                sum += e0 + e1;
            }
        }
        sum += __shfl_xor(sum, 16);
        sum += __shfl_xor(sum, 32);
        const float inv = __builtin_amdgcn_rcpf(sum);

        // normalize + pack P to bf16 pairs (lane-local: pixel n's kcols)
        unsigned int pa[7], pb[7], pc[7], pd[7];
        #pragma unroll
        for (int i = 0; i < 7; ++i) {
            pa[i] = cvtpk_bf16(s0[i][0] * inv, s0[i][1] * inv);
            pb[i] = cvtpk_bf16(s0[i][2] * inv, s0[i][3] * inv);
            pc[i] = cvtpk_bf16(s1[i][0] * inv, s1[i][1] * inv);
            pd[i] = cvtpk_bf16(s1[i][2] * inv, s1[i][3] * inv);
        }

        // PV: acc[w][ch] += P'[w][kcol] * Vt[ch][kcol] over 7 tap-rows
        f32x4 acc0 = z4, acc1 = z4;
        #pragma unroll
        for (int i = 0; i < 7; ++i) {
            const int a0s = __shfl((int)pa[i], src0);
            const int c0s = __shfl((int)pc[i], src0);
            const int b0s = __shfl((int)pb[i], src0);
            const int d0s = __shfl((int)pd[i], src0);
            const int a1s = __shfl((int)pa[i], src1);
            const int c1s = __shfl((int)pc[i], src1);
            const int b1s = __shfl((int)pb[i], src1);
            const int d1s = __shfl((int)pd[i], src1);
            union { unsigned int u[4]; bf16x8 v; } pu;
            pu.u[0] = (unsigned int)(hi2 ? c0s : a0s);
            pu.u[1] = (unsigned int)(hi2 ? d0s : b0s);
            pu.u[2] = (unsigned int)(hi2 ? c1s : a1s);
            pu.u[3] = (unsigned int)(hi2 ? d1s : b1s);
            const unsigned short* vr = &vt[(hl + i) * 24 + g * 8];
            bf16x8 vf0 = *(const bf16x8*)(vr + n * 536);
            bf16x8 vf1 = *(const bf16x8*)(vr + (n + 16) * 536);
            acc0 = __builtin_amdgcn_mfma_f32_16x16x32_bf16(pu.v, vf0, acc0, 0, 0, 0);
            acc1 = __builtin_amdgcn_mfma_f32_16x16x32_bf16(pu.v, vf1, acc1, 0, 0, 0);
        }

        // store: lane holds O[w = g*4+r][ch = n / n+16]
        if (h < HH) {
            unsigned short* ap = A + (pxb + h * WW) * 256 + co + n;
            const int wp = w0 + g * 4;
            #pragma unroll
            for (int r = 0; r < 4; ++r) {
                if (wp + r < WW) {
                    ap[(size_t)(wp + r) * 256]      = f2bf(acc0[r]);
                    ap[(size_t)(wp + r) * 256 + 16] = f2bf(acc1[r]);
                }
            }
        }
    }
}

// ---------------------------------------------------------------------------
// LN1: wave-per-pixel over contiguous 256 channels (NHWC fp32 in, bf16 out).
// ---------------------------------------------------------------------------
__global__ __launch_bounds__(256) void ln1_k(
    const float* __restrict__ X, const float* __restrict__ g,
    const float* __restrict__ bt, unsigned short* __restrict__ XLb)
{
    const int wv = threadIdx.x >> 6, lane = threadIdx.x & 63;
    const size_t px = (size_t)blockIdx.x * 4 + wv;
    const float4 v = *(const float4*)(X + px * 256 + lane * 4);
    float s = v.x + v.y + v.z + v.w;
    float ss = v.x * v.x + v.y * v.y + v.z * v.z + v.w * v.w;
    #pragma unroll
    for (int o = 32; o; o >>= 1) { s += __shfl_xor(s, o); ss += __shfl_xor(ss, o); }
    const float mu = s * (1.0f / 256.0f);
    const float var = ss * (1.0f / 256.0f) - mu * mu;
    const float rs = rsqrtf(var + 1e-5f);
    const float4 gv = *(const float4*)(g + lane * 4);
    const float4 bv = *(const float4*)(bt + lane * 4);
    ushort4 o4;
    o4.x = f2bf((v.x - mu) * rs * gv.x + bv.x);
    o4.y = f2bf((v.y - mu) * rs * gv.y + bv.y);
    o4.z = f2bf((v.z - mu) * rs * gv.z + bv.z);
    o4.w = f2bf((v.w - mu) * rs * gv.w + bv.w);
    *(ushort4*)(XLb + px * 256 + lane * 4) = o4;
}

// ---------------------------------------------------------------------------
// LN2: (bf16 XL + fp32 Y2) -> LN -> NCHW fp32 out, via LDS transpose.
// ---------------------------------------------------------------------------
__global__ __launch_bounds__(256) void ln2_k(
    const unsigned short* __restrict__ XLb, const float* __restrict__ Y2,
    const float* __restrict__ g, const float* __restrict__ bt,
    float* __restrict__ Out)
{
    __shared__ float T[256 * 33];
    const int px0 = blockIdx.x * 32;
    const int bb = px0 / HWSZ, hw0 = px0 - bb * HWSZ;
    const int t = threadIdx.x, wv = t >> 6, lane = t & 63;
    const float4 gv = *(const float4*)(g + lane * 4);
    const float4 bv = *(const float4*)(bt + lane * 4);
    #pragma unroll
    for (int it = 0; it < 8; ++it) {
        const int pxl = wv * 8 + it;
        const size_t px = (size_t)px0 + pxl;
        const ushort4 xb = *(const ushort4*)(XLb + px * 256 + lane * 4);
        const float4 y = *(const float4*)(Y2 + px * 256 + lane * 4);
        float4 v;
        v.x = bf2f(xb.x) + y.x; v.y = bf2f(xb.y) + y.y;
        v.z = bf2f(xb.z) + y.z; v.w = bf2f(xb.w) + y.w;
        float s = v.x + v.y + v.z + v.w;
        float ss = v.x * v.x + v.y * v.y + v.z * v.z + v.w * v.w;
        #pragma unroll
        for (int o = 32; o; o >>= 1) { s += __shfl_xor(s, o); ss += __shfl_xor(ss, o); }
        const float mu = s * (1.0f / 256.0f);
        const float rs = rsqrtf(ss * (1.0f / 256.0f) - mu * mu + 1e-5f);
        T[(lane * 4 + 0) * 33 + pxl] = (v.x - mu) * rs * gv.x + bv.x;
        T[(lane * 4 + 1) * 33 + pxl] = (v.y - mu) * rs * gv.y + bv.y;
        T[(lane * 4 + 2) * 33 + pxl] = (v.z - mu) * rs * gv.z + bv.z;
        T[(lane * 4 + 3) * 33 + pxl] = (v.w - mu) * rs * gv.w + bv.w;
    }
    __syncthreads();
    #pragma unroll
    for (int pass = 0; pass < 32; ++pass) {
        const int idx = t + pass * 256;
        const int c = idx >> 5, pxl = idx & 31;
        Out[((size_t)(bb * 256 + c)) * HWSZ + hw0 + pxl] = T[c * 33 + pxl];
    }
}

// ---------------------------------------------------------------------------
// Workspace layout unchanged (216.6 MB); see previous revision.
// ---------------------------------------------------------------------------
extern "C" void kernel_launch(void* const* d_in, const int* in_sizes, int n_in,
                              void* d_out, int out_size, void* d_ws, size_t ws_size,
                              hipStream_t stream)
{
    const float* F_lidar = (const float*)d_in[0];
    const float* F_cam   = (const float*)d_in[1];
    const float* Wq  = (const float*)d_in[2];
    const float* Wk  = (const float*)d_in[3];
    const float* Wv  = (const float*)d_in[4];
    const float* Wo  = (const float*)d_in[5];
    const float* Wr  = (const float*)d_in[6];
    const float* g1  = (const float*)d_in[7];
    const float* b1  = (const float*)d_in[8];
    const float* g2  = (const float*)d_in[9];
    const float* b2  = (const float*)d_in[10];
    const float* W1  = (const float*)d_in[11];
    const float* bf1 = (const float*)d_in[12];
    const float* W2  = (const float*)d_in[13];
    const float* bf2 = (const float*)d_in[14];

    char* wsb = (char*)d_ws;
    unsigned short* Fl  = (unsigned short*)(wsb);
    unsigned short* Fc  = (unsigned short*)(wsb + 10240000);
    unsigned short* Qb  = (unsigned short*)(wsb + 51200000);
    unsigned short* Kb  = (unsigned short*)(wsb + 92160000);
    unsigned short* Vb  = (unsigned short*)(wsb + 133120000);
    float*          Y2  = (float*)(wsb + 92160000);      // overlays Kb+Vb
    unsigned short* Y1  = Fc;                             // overlays Fc
    unsigned short* XLb = (unsigned short*)(wsb + 174080000);
    unsigned short* Wq_b = (unsigned short*)(wsb + 215040000);
    unsigned short* Wk_b = Wq_b + 16384;
    unsigned short* Wv_b = Wk_b + 65536;
    unsigned short* Wcat = Wv_b + 65536;
    unsigned short* W1t  = Wcat + 81920;
    unsigned short* W2t  = W1t + 262144;
    float* XW  = (float*)d_out;
    float* out = (float*)d_out;

    const dim3 blk(256);

    cvt_weights<<<dim3(1024, 6), blk, 0, stream>>>(Wq, Wk, Wv, Wo, Wr, W1, W2,
        Wq_b, Wk_b, Wv_b, Wcat, W1t, W2t);
    to_nhwc<<<dim3(625, 1, 2), blk, 0, stream>>>(F_lidar, Fl, 64);
    to_nhwc<<<dim3(625, 4, 2), blk, 0, stream>>>(F_cam, Fc, 256);

    // Q/K/V projections (bf16 out)
    gemm_bf16<<<dim3(625, 2), blk, 0, stream>>>(Fl, 64, Fl, 64, 64,
        Wq_b, 64, 64, Qb, nullptr, nullptr, 0);
    gemm_bf16<<<dim3(625, 2), blk, 0, stream>>>(Fc, 256, Fc, 256, 256,
        Wk_b, 256, 256, Kb, nullptr, nullptr, 0);
    gemm_bf16<<<dim3(625, 2), blk, 0, stream>>>(Fc, 256, Fc, 256, 256,
        Wv_b, 256, 256, Vb, nullptr, nullptr, 0);

    // attention (A overwrites Q in-place; each block touches only its tile)
    attn_bf16<<<dim3(169, 8, 2), blk, 0, stream>>>(Qb, Kb, Vb, Qb);

    // fused out-proj + lidar residual: K=320 concat GEMM -> fp32 XW (d_out)
    gemm_bf16<<<dim3(625, 2), blk, 0, stream>>>(Qb, 256, Fl, 64, 256,
        Wcat, 320, 320, nullptr, XW, nullptr, 0);

    // LN1 -> bf16 XLb
    ln1_k<<<dim3(20000), blk, 0, stream>>>(XW, g1, b1, XLb);

    // FFN, hidden chunked 4 x 256
    for (int c = 0; c < 4; ++c) {
        gemm_bf16<<<dim3(625, 2), blk, 0, stream>>>(XLb, 256, XLb, 256, 256,
            W1t + (size_t)c * 65536, 256, 256, Y1, nullptr, bf1 + c * 256, 1);
        gemm_bf16<<<dim3(625, 2), blk, 0, stream>>>(Y1, 256, Y1, 256, 256,
            W2t + c * 256, 1024, 256, nullptr, Y2,
            (c == 0) ? bf2 : nullptr, (c == 0) ? 0 : 2);
    }

    // LN2 (XLb + Y2) -> final NCHW output
    ln2_k<<<dim3(2500), blk, 0, stream>>>(XLb, Y2, g2, b2, out);
}

// Round 4
// 733.988 us; speedup vs baseline: 1.4063x; 1.2146x over previous
//
#include <hip/hip_runtime.h>
#include <stdint.h>

#define HH 200
#define WW 200
#define HWSZ 40000
#define NPX 80000

typedef __attribute__((ext_vector_type(8))) short bf16x8;
typedef __attribute__((ext_vector_type(4))) float f32x4;

__device__ __forceinline__ float bf2f(unsigned short u) {
    union { uint32_t i; float f; } c; c.i = ((uint32_t)u) << 16; return c.f;
}
__device__ __forceinline__ unsigned short f2bf(float f) {
    union { float f; uint32_t i; } c; c.f = f;
    uint32_t r = c.i + 0x7FFF + ((c.i >> 16) & 1);   // RNE
    return (unsigned short)(r >> 16);
}
__device__ __forceinline__ unsigned int cvtpk_bf16(float lo, float hi) {
    unsigned int r;
    asm("v_cvt_pk_bf16_f32 %0, %1, %2" : "=v"(r) : "v"(lo), "v"(hi));
    return r;
}

// ---------------------------------------------------------------------------
// Weight conversion: fp32 -> bf16; W1/W2 transposed to [cout][cin];
// Wcat = concat(Wo, Wr) along k (k<256 -> Wo, k>=256 -> Wr).
// ---------------------------------------------------------------------------
__global__ __launch_bounds__(256) void cvt_weights(
    const float* __restrict__ Wq, const float* __restrict__ Wk,
    const float* __restrict__ Wv, const float* __restrict__ Wo,
    const float* __restrict__ Wr, const float* __restrict__ W1,
    const float* __restrict__ W2,
    unsigned short* Wq_b, unsigned short* Wk_b, unsigned short* Wv_b,
    unsigned short* Wcat, unsigned short* W1t, unsigned short* W2t)
{
    const int seg = blockIdx.y;
    const int idx = blockIdx.x * 256 + threadIdx.x;
    if (seg == 0)      { if (idx < 16384) Wq_b[idx] = f2bf(Wq[idx]); }
    else if (seg == 1) { if (idx < 65536) Wk_b[idx] = f2bf(Wk[idx]); }
    else if (seg == 2) { if (idx < 65536) Wv_b[idx] = f2bf(Wv[idx]); }
    else if (seg == 3) {
        if (idx < 81920) {
            int r = idx / 320, k = idx - r * 320;
            Wcat[idx] = f2bf(k < 256 ? Wo[r * 256 + k] : Wr[r * 64 + (k - 256)]);
        }
    } else if (seg == 4) {
        if (idx < 262144) { int o = idx >> 8, i = idx & 255; W1t[idx] = f2bf(W1[i * 1024 + o]); }
    } else {
        if (idx < 262144) { int o = idx >> 10, i = idx & 1023; W2t[idx] = f2bf(W2[i * 256 + o]); }
    }
}

// ---------------------------------------------------------------------------
// NCHW fp32 -> NHWC bf16 (64px x 64c LDS tile).
// ---------------------------------------------------------------------------
__global__ __launch_bounds__(256) void to_nhwc(
    const float* __restrict__ src, unsigned short* __restrict__ dst, int C)
{
    __shared__ unsigned short T[64][72];
    const int b = blockIdx.z, c0 = blockIdx.y * 64, px0 = blockIdx.x * 64;
    const int t = threadIdx.x;
    const int pxl = t & 63, cl0 = t >> 6;
    const float* sp = src + ((size_t)(b * C + c0 + cl0)) * HWSZ + px0 + pxl;
    #pragma unroll
    for (int i = 0; i < 16; ++i)
        T[pxl][cl0 + i * 4] = f2bf(sp[(size_t)i * 4 * HWSZ]);
    __syncthreads();
    #pragma unroll
    for (int r = 0; r < 2; ++r) {
        int idx = t + r * 256;
        int p = idx >> 3, cof = (idx & 7) * 8;
        uint4 v = *(const uint4*)&T[p][cof];
        *(uint4*)(dst + ((size_t)(b * HWSZ + px0 + p)) * C + c0 + cof) = v;
    }
}

// ---------------------------------------------------------------------------
// bf16 MFMA GEMM (NHWC activations x row-major [cout][cin] weights).
// Out[px][cout] = sum_k In[px][k] * W[cout][k]; M=80000, tile 128x128, BK=32.
// Optional concat second input (k >= K1 -> In2). Out: bf16 (OutB, row stride
// outStride) or fp32 (OutF, stride 256). flags: 1=relu, 2=fp32 accumulate.
// ---------------------------------------------------------------------------
__global__ __launch_bounds__(256) void gemm_bf16(
    const unsigned short* __restrict__ In, int inStride,
    const unsigned short* __restrict__ In2, int in2Stride, int K1,
    const unsigned short* __restrict__ Wb, int wStride, int Ktot,
    unsigned short* __restrict__ OutB, float* __restrict__ OutF,
    const float* __restrict__ bias, int flags, int outStride)
{
    __shared__ bf16x8 AB[1024];   // [0..511] A frags, [512..1023] B frags
    const int t = threadIdx.x;
    const int px0 = blockIdx.x * 128;
    const int n0 = blockIdx.y * 128;
    const int lane = t & 63, w = t >> 6;
    const int mh = w & 1, nh = w >> 1;

    f32x4 acc[4][4] = {};

    for (int k0 = 0; k0 < Ktot; k0 += 32) {
        #pragma unroll
        for (int r = 0; r < 2; ++r) {
            const int c = t + r * 256;
            const int l = c & 63;
            const int ko = k0 + ((l >> 4) << 3);
            {
                const int mt = c >> 6;
                const int px = px0 + mt * 16 + (l & 15);
                const unsigned short* sp = (ko < K1)
                    ? (In  + (size_t)px * inStride  + ko)
                    : (In2 + (size_t)px * in2Stride + (ko - K1));
                AB[c] = *(const bf16x8*)sp;
            }
            {
                const int nt = c >> 6;
                const int cc = n0 + nt * 16 + (l & 15);
                AB[512 + c] = *(const bf16x8*)(Wb + (size_t)cc * wStride + ko);
            }
        }
        __syncthreads();
        bf16x8 av[4], bv[4];
        #pragma unroll
        for (int i = 0; i < 4; ++i) av[i] = AB[(mh * 4 + i) * 64 + lane];
        #pragma unroll
        for (int j = 0; j < 4; ++j) bv[j] = AB[512 + (nh * 4 + j) * 64 + lane];
        #pragma unroll
        for (int i = 0; i < 4; ++i)
            #pragma unroll
            for (int j = 0; j < 4; ++j)
                acc[i][j] = __builtin_amdgcn_mfma_f32_16x16x32_bf16(
                    av[i], bv[j], acc[i][j], 0, 0, 0);
        __syncthreads();
    }

    const int q = lane >> 4, ln = lane & 15;
    const bool relu = (flags & 1) != 0, accum = (flags & 2) != 0;
    #pragma unroll
    for (int i = 0; i < 4; ++i) {
        #pragma unroll
        for (int j = 0; j < 4; ++j) {
            const int coutv = n0 + nh * 64 + j * 16 + ln;
            const float bval = bias ? bias[coutv] : 0.0f;
            #pragma unroll
            for (int r = 0; r < 4; ++r) {
                const int px = px0 + mh * 64 + i * 16 + q * 4 + r;
                float v = acc[i][j][r] + bval;
                if (relu) v = fmaxf(v, 0.0f);
                if (OutB) {
                    OutB[(size_t)px * outStride + coutv] = f2bf(v);
                } else {
                    float* op = OutF + (size_t)px * 256 + coutv;
                    if (accum) v += *op;
                    *op = v;
                }
            }
        }
    }
}

// ---------------------------------------------------------------------------
// Fused FFN-2nd-half + LN2: Out = LN(XLb + Y1*W2t + bf2) -> NCHW fp32.
// Block = 512 thr (8 waves), tile 128 px x 256 cout (FULL rows), K=1024.
// Wave (mh, nh) computes a 64px x 64col quadrant pair; epilogue:
//   acc += bf2[col] + XLb residual; per-pixel LN stats via 16-lane shfl
//   reduce + 4-way nh partials in LDS; normalized tile written NCHW via
//   chunked (4 x 32px) LDS transpose. Eliminates Y2 buffer + ln2 pass.
// ---------------------------------------------------------------------------
__global__ __launch_bounds__(512) void ffn2_ln2(
    const unsigned short* __restrict__ Y1,   // [NPX][1024] bf16 (relu'd)
    const unsigned short* __restrict__ XLb,  // [NPX][256]  bf16 residual
    const unsigned short* __restrict__ W2t,  // [256][1024] bf16
    const float* __restrict__ bf2v,          // [256]
    const float* __restrict__ g2, const float* __restrict__ b2,
    float* __restrict__ Out)                 // [2][256][HWSZ] fp32
{
    __shared__ union {
        bf16x8 AB[1536];          // 8 A frags + 16 B frags (24 KB)
        float  T[256 * 33];       // transpose buffer (33.8 KB)
    } sm;
    __shared__ float part_s[4][128], part_q[4][128];

    const int t = threadIdx.x;
    const int px0 = blockIdx.x * 128;
    const int lane = t & 63, w = t >> 6;
    const int mh = w & 1, nh = w >> 1;          // mh: px half, nh: col quarter
    const int q = lane >> 4, ln = lane & 15;

    f32x4 acc[4][4] = {};

    for (int k0 = 0; k0 < 1024; k0 += 32) {
        #pragma unroll
        for (int r = 0; r < 3; ++r) {
            const int c = t + r * 512;           // 0..1535
            const int l = c & 63;
            const int ko = k0 + ((l >> 4) << 3);
            if (c < 512) {                       // A frags: 8 m-tiles
                const int mt = c >> 6;
                const int px = px0 + mt * 16 + (l & 15);
                sm.AB[c] = *(const bf16x8*)(Y1 + (size_t)px * 1024 + ko);
            } else {                             // B frags: 16 n-tiles
                const int c2 = c - 512;
                const int nt = c2 >> 6;
                const int cc = nt * 16 + (l & 15);
                sm.AB[c] = *(const bf16x8*)(W2t + (size_t)cc * 1024 + ko);
            }
        }
        __syncthreads();
        bf16x8 av[4], bv[4];
        #pragma unroll
        for (int i = 0; i < 4; ++i) av[i] = sm.AB[(mh * 4 + i) * 64 + lane];
        #pragma unroll
        for (int j = 0; j < 4; ++j) bv[j] = sm.AB[512 + (nh * 4 + j) * 64 + lane];
        #pragma unroll
        for (int i = 0; i < 4; ++i)
            #pragma unroll
            for (int j = 0; j < 4; ++j)
                acc[i][j] = __builtin_amdgcn_mfma_f32_16x16x32_bf16(
                    av[i], bv[j], acc[i][j], 0, 0, 0);
        __syncthreads();
    }

    // per-column constants
    float biasv[4], gv[4], bvv[4];
    #pragma unroll
    for (int j = 0; j < 4; ++j) {
        const int col = nh * 64 + j * 16 + ln;
        biasv[j] = bf2v[col];
        gv[j] = g2[col];
        bvv[j] = b2[col];
    }

    // residual + partial stats (sum over this wave's 64 cols per pixel)
    #pragma unroll
    for (int i = 0; i < 4; ++i) {
        #pragma unroll
        for (int r = 0; r < 4; ++r) {
            const int pl = mh * 64 + i * 16 + q * 4 + r;
            const size_t px = (size_t)px0 + pl;
            float s = 0.0f, ssq = 0.0f;
            #pragma unroll
            for (int j = 0; j < 4; ++j) {
                const int col = nh * 64 + j * 16 + ln;
                float v = acc[i][j][r] + biasv[j] + bf2f(XLb[px * 256 + col]);
                acc[i][j][r] = v;
                s += v; ssq += v * v;
            }
            #pragma unroll
            for (int o = 1; o <= 8; o <<= 1) {
                s += __shfl_xor(s, o); ssq += __shfl_xor(ssq, o);
            }
            if (ln == 0) { part_s[nh][pl] = s; part_q[nh][pl] = ssq; }
        }
    }
    __syncthreads();

    float muv[4][4], rsv[4][4];
    #pragma unroll
    for (int i = 0; i < 4; ++i) {
        #pragma unroll
        for (int r = 0; r < 4; ++r) {
            const int pl = mh * 64 + i * 16 + q * 4 + r;
            const float s  = part_s[0][pl] + part_s[1][pl] + part_s[2][pl] + part_s[3][pl];
            const float sq = part_q[0][pl] + part_q[1][pl] + part_q[2][pl] + part_q[3][pl];
            const float mu = s * (1.0f / 256.0f);
            muv[i][r] = mu;
            rsv[i][r] = rsqrtf(sq * (1.0f / 256.0f) - mu * mu + 1e-5f);
        }
    }
    __syncthreads();   // done with sm.AB; reuse as sm.T

    // chunked transpose + NCHW write (chunk = 32 pixels)
    #pragma unroll
    for (int ck = 0; ck < 4; ++ck) {
        if (mh == (ck >> 1)) {
            const int ib = (ck & 1) * 2;
            #pragma unroll
            for (int ii = 0; ii < 2; ++ii) {
                const int i = ib + ii;
                #pragma unroll
                for (int j = 0; j < 4; ++j) {
                    const int col = nh * 64 + j * 16 + ln;
                    #pragma unroll
                    for (int r = 0; r < 4; ++r) {
                        sm.T[col * 33 + ii * 16 + q * 4 + r] =
                            (acc[i][j][r] - muv[i][r]) * rsv[i][r] * gv[j] + bvv[j];
                    }
                }
            }
        }
        __syncthreads();
        const int pxc = px0 + ck * 32;          // 32-aligned; 40000%32==0 so
        const int bb = pxc / HWSZ;              // no mid-chunk batch crossing
        const int hw0 = pxc - bb * HWSZ;
        #pragma unroll
        for (int p = 0; p < 16; ++p) {
            const int idx = t + p * 512;
            const int c = idx >> 5, pxl = idx & 31;
            Out[((size_t)(bb * 256 + c)) * HWSZ + hw0 + pxl] = sm.T[c * 33 + pxl];
        }
        __syncthreads();
    }
}

// ---------------------------------------------------------------------------
// 7x7 local-window attention via MFMA, NHWC bf16, replicate pad via clamp.
// (unchanged — see round-2 notes)
// ---------------------------------------------------------------------------
__global__ __launch_bounds__(256) void attn_bf16(
    const unsigned short* Q, const unsigned short* __restrict__ K,
    const unsigned short* __restrict__ V, unsigned short* A)
{
    __shared__ __align__(16) unsigned short vt[32 * 536];   // 34304 B
    const int b = blockIdx.z, head = blockIdx.y;
    const int tiy = blockIdx.x / 13, tix = blockIdx.x % 13;
    const int h0 = tiy * 16, w0 = tix * 16;
    const int t = threadIdx.x;
    const int lane = t & 63, wv = t >> 6;
    const int g = lane >> 4, n = lane & 15;
    const int co = head * 32;
    const size_t pxb = (size_t)b * HWSZ;

    for (int idx = t; idx < 832; idx += 256) {
        if (idx < 704) {
            int ch = idx / 22, r = idx - ch * 22;
            *(unsigned int*)&vt[ch * 536 + r * 24 + 22] = 0u;
        } else {
            int k2 = idx - 704;
            int ch = k2 >> 2, e = k2 & 3;
            *(unsigned int*)&vt[ch * 536 + 528 + e * 2] = 0u;
        }
    }
    for (int idx = t; idx < 484 * 4; idx += 256) {
        int pos = idx >> 2, chunk = idx & 3;
        int r = pos / 22, c = pos - r * 22;
        int gh = min(max(h0 + r - 3, 0), HH - 1);
        int gw = min(max(w0 + c - 3, 0), WW - 1);
        bf16x8 v8 = *(const bf16x8*)(V + (pxb + gh * WW + gw) * 256 + co + chunk * 8);
        unsigned short* dp = &vt[(chunk * 8) * 536 + r * 24 + c];
        #pragma unroll
        for (int e = 0; e < 8; ++e) dp[e * 536] = (unsigned short)v8[e];
    }
    __syncthreads();

    const f32x4 z4 = {0.f, 0.f, 0.f, 0.f};
    const int qw  = min(w0 + n, WW - 1);
    const int kc0 = min(max(w0 - 3 + n, 0), WW - 1);
    const int kc1 = min(w0 + 13 + n, WW - 1);
    const bool hi2 = (g >> 1) != 0;
    const int src0 = ((g & 1) * 2) * 16 + n;
    const int src1 = src0 + 16;

    for (int hh = 0; hh < 4; ++hh) {
        const int hl = wv * 4 + hh;
        const int h = h0 + hl;
        const int hc = min(h, HH - 1);

        const bf16x8 qf = *(const bf16x8*)(Q + (pxb + hc * WW + qw) * 256 + co + g * 8);

        f32x4 s0[7], s1[7];
        #pragma unroll
        for (int i = 0; i < 7; ++i) {
            const int gh = min(max(h - 3 + i, 0), HH - 1);
            const unsigned short* kr = K + (pxb + gh * WW) * 256 + co + g * 8;
            bf16x8 a0 = *(const bf16x8*)(kr + (size_t)kc0 * 256);
            bf16x8 a1 = *(const bf16x8*)(kr + (size_t)kc1 * 256);
            s0[i] = __builtin_amdgcn_mfma_f32_16x16x32_bf16(a0, qf, z4, 0, 0, 0);
            s1[i] = __builtin_amdgcn_mfma_f32_16x16x32_bf16(a1, qf, z4, 0, 0, 0);
        }

        float mx = -3.0e38f;
        #pragma unroll
        for (int r = 0; r < 4; ++r) {
            float m0 = s0[0][r], m1 = s1[0][r];
            #pragma unroll
            for (int i = 1; i < 7; ++i) {
                m0 = fmaxf(m0, s0[i][r]);
                m1 = fmaxf(m1, s1[i][r]);
            }
            const int k0 = 4 * g + r, k1 = k0 + 16;
            mx = fmaxf(mx, ((unsigned)(k0 - n) <= 6u) ? m0 : -3.0e38f);
            mx = fmaxf(mx, ((unsigned)(k1 - n) <= 6u) ? m1 : -3.0e38f);
        }
        mx = fmaxf(mx, __shfl_xor(mx, 16));
        mx = fmaxf(mx, __shfl_xor(mx, 32));

        float sum = 0.0f;
        #pragma unroll
        for (int r = 0; r < 4; ++r) {
            const int k0 = 4 * g + r, k1 = k0 + 16;
            const bool in0 = (unsigned)(k0 - n) <= 6u;
            const bool in1 = (unsigned)(k1 - n) <= 6u;
            #pragma unroll
            for (int i = 0; i < 7; ++i) {
                float e0 = in0 ? __expf((s0[i][r] - mx) * 0.17677669529663687f) : 0.0f;
                float e1 = in1 ? __expf((s1[i][r] - mx) * 0.17677669529663687f) : 0.0f;
                s0[i][r] = e0; s1[i][r] = e1;
                sum += e0 + e1;
            }
        }
        sum += __shfl_xor(sum, 16);
        sum += __shfl_xor(sum, 32);
        const float inv = __builtin_amdgcn_rcpf(sum);

        unsigned int pa[7], pb[7], pc[7], pd[7];
        #pragma unroll
        for (int i = 0; i < 7; ++i) {
            pa[i] = cvtpk_bf16(s0[i][0] * inv, s0[i][1] * inv);
            pb[i] = cvtpk_bf16(s0[i][2] * inv, s0[i][3] * inv);
            pc[i] = cvtpk_bf16(s1[i][0] * inv, s1[i][1] * inv);
            pd[i] = cvtpk_bf16(s1[i][2] * inv, s1[i][3] * inv);
        }

        f32x4 acc0 = z4, acc1 = z4;
        #pragma unroll
        for (int i = 0; i < 7; ++i) {
            const int a0s = __shfl((int)pa[i], src0);
            const int c0s = __shfl((int)pc[i], src0);
            const int b0s = __shfl((int)pb[i], src0);
            const int d0s = __shfl((int)pd[i], src0);
            const int a1s = __shfl((int)pa[i], src1);
            const int c1s = __shfl((int)pc[i], src1);
            const int b1s = __shfl((int)pb[i], src1);
            const int d1s = __shfl((int)pd[i], src1);
            union { unsigned int u[4]; bf16x8 v; } pu;
            pu.u[0] = (unsigned int)(hi2 ? c0s : a0s);
            pu.u[1] = (unsigned int)(hi2 ? d0s : b0s);
            pu.u[2] = (unsigned int)(hi2 ? c1s : a1s);
            pu.u[3] = (unsigned int)(hi2 ? d1s : b1s);
            const unsigned short* vr = &vt[(hl + i) * 24 + g * 8];
            bf16x8 vf0 = *(const bf16x8*)(vr + n * 536);
            bf16x8 vf1 = *(const bf16x8*)(vr + (n + 16) * 536);
            acc0 = __builtin_amdgcn_mfma_f32_16x16x32_bf16(pu.v, vf0, acc0, 0, 0, 0);
            acc1 = __builtin_amdgcn_mfma_f32_16x16x32_bf16(pu.v, vf1, acc1, 0, 0, 0);
        }

        if (h < HH) {
            unsigned short* ap = A + (pxb + h * WW) * 256 + co + n;
            const int wp = w0 + g * 4;
            #pragma unroll
            for (int r = 0; r < 4; ++r) {
                if (wp + r < WW) {
                    ap[(size_t)(wp + r) * 256]      = f2bf(acc0[r]);
                    ap[(size_t)(wp + r) * 256 + 16] = f2bf(acc1[r]);
                }
            }
        }
    }
}

// ---------------------------------------------------------------------------
// LN1: wave-per-pixel over contiguous 256 channels (NHWC fp32 in, bf16 out).
// ---------------------------------------------------------------------------
__global__ __launch_bounds__(256) void ln1_k(
    const float* __restrict__ X, const float* __restrict__ g,
    const float* __restrict__ bt, unsigned short* __restrict__ XLb)
{
    const int wv = threadIdx.x >> 6, lane = threadIdx.x & 63;
    const size_t px = (size_t)blockIdx.x * 4 + wv;
    const float4 v = *(const float4*)(X + px * 256 + lane * 4);
    float s = v.x + v.y + v.z + v.w;
    float ss = v.x * v.x + v.y * v.y + v.z * v.z + v.w * v.w;
    #pragma unroll
    for (int o = 32; o; o >>= 1) { s += __shfl_xor(s, o); ss += __shfl_xor(ss, o); }
    const float mu = s * (1.0f / 256.0f);
    const float var = ss * (1.0f / 256.0f) - mu * mu;
    const float rs = rsqrtf(var + 1e-5f);
    const float4 gv = *(const float4*)(g + lane * 4);
    const float4 bv = *(const float4*)(bt + lane * 4);
    ushort4 o4;
    o4.x = f2bf((v.x - mu) * rs * gv.x + bv.x);
    o4.y = f2bf((v.y - mu) * rs * gv.y + bv.y);
    o4.z = f2bf((v.z - mu) * rs * gv.z + bv.z);
    o4.w = f2bf((v.w - mu) * rs * gv.w + bv.w);
    *(ushort4*)(XLb + px * 256 + lane * 4) = o4;
}

// ---------------------------------------------------------------------------
// Workspace (bytes):                                      total 216.6 MB
//   0         : Fl_bf  [80000][64]  bf16   (10.24 MB)
//   10240000  : Fc_bf  [80000][256] bf16   (40.96)  ┐ after Wcat gemm this
//   51200000  : Qb/Ab  [80000][256] bf16   (40.96)  ├ whole 163.84 MB region
//   92160000  : Kb, Vb [2x 40.96]                   ┘ becomes Y1 [80000][1024]
//   174080000 : XLb    [80000][256] bf16   (40.96)
//   215040000 : bf16 weights (~1.5 MB)
//   d_out     : XW fp32 NHWC scratch (consumed by ln1), then final NCHW out
// ---------------------------------------------------------------------------
extern "C" void kernel_launch(void* const* d_in, const int* in_sizes, int n_in,
                              void* d_out, int out_size, void* d_ws, size_t ws_size,
                              hipStream_t stream)
{
    const float* F_lidar = (const float*)d_in[0];
    const float* F_cam   = (const float*)d_in[1];
    const float* Wq  = (const float*)d_in[2];
    const float* Wk  = (const float*)d_in[3];
    const float* Wv  = (const float*)d_in[4];
    const float* Wo  = (const float*)d_in[5];
    const float* Wr  = (const float*)d_in[6];
    const float* g1  = (const float*)d_in[7];
    const float* b1  = (const float*)d_in[8];
    const float* g2  = (const float*)d_in[9];
    const float* b2  = (const float*)d_in[10];
    const float* W1  = (const float*)d_in[11];
    const float* bf1 = (const float*)d_in[12];
    const float* W2  = (const float*)d_in[13];
    const float* bf2 = (const float*)d_in[14];

    char* wsb = (char*)d_ws;
    unsigned short* Fl  = (unsigned short*)(wsb);
    unsigned short* Fc  = (unsigned short*)(wsb + 10240000);
    unsigned short* Qb  = (unsigned short*)(wsb + 51200000);
    unsigned short* Kb  = (unsigned short*)(wsb + 92160000);
    unsigned short* Vb  = (unsigned short*)(wsb + 133120000);
    unsigned short* Y1b = Fc;                             // [80000][1024] bf16
    unsigned short* XLb = (unsigned short*)(wsb + 174080000);
    unsigned short* Wq_b = (unsigned short*)(wsb + 215040000);
    unsigned short* Wk_b = Wq_b + 16384;
    unsigned short* Wv_b = Wk_b + 65536;
    unsigned short* Wcat = Wv_b + 65536;
    unsigned short* W1t  = Wcat + 81920;
    unsigned short* W2t  = W1t + 262144;
    float* XW  = (float*)d_out;
    float* out = (float*)d_out;

    const dim3 blk(256);

    cvt_weights<<<dim3(1024, 6), blk, 0, stream>>>(Wq, Wk, Wv, Wo, Wr, W1, W2,
        Wq_b, Wk_b, Wv_b, Wcat, W1t, W2t);
    to_nhwc<<<dim3(625, 1, 2), blk, 0, stream>>>(F_lidar, Fl, 64);
    to_nhwc<<<dim3(625, 4, 2), blk, 0, stream>>>(F_cam, Fc, 256);

    // Q/K/V projections (bf16 out)
    gemm_bf16<<<dim3(625, 2), blk, 0, stream>>>(Fl, 64, Fl, 64, 64,
        Wq_b, 64, 64, Qb, nullptr, nullptr, 0, 256);
    gemm_bf16<<<dim3(625, 2), blk, 0, stream>>>(Fc, 256, Fc, 256, 256,
        Wk_b, 256, 256, Kb, nullptr, nullptr, 0, 256);
    gemm_bf16<<<dim3(625, 2), blk, 0, stream>>>(Fc, 256, Fc, 256, 256,
        Wv_b, 256, 256, Vb, nullptr, nullptr, 0, 256);

    // attention (A overwrites Q in-place; each block touches only its tile)
    attn_bf16<<<dim3(169, 8, 2), blk, 0, stream>>>(Qb, Kb, Vb, Qb);

    // fused out-proj + lidar residual: K=320 concat GEMM -> fp32 XW (d_out)
    gemm_bf16<<<dim3(625, 2), blk, 0, stream>>>(Qb, 256, Fl, 64, 256,
        Wcat, 320, 320, nullptr, XW, nullptr, 0, 256);

    // LN1 -> bf16 XLb
    ln1_k<<<dim3(20000), blk, 0, stream>>>(XW, g1, b1, XLb);

    // FFN half 1: full-width hidden, one dispatch (relu + bias), Y1 bf16
    gemm_bf16<<<dim3(625, 8), blk, 0, stream>>>(XLb, 256, XLb, 256, 256,
        W1t, 256, 256, Y1b, nullptr, bf1, 1, 1024);

    // FFN half 2 fused with residual + LN2 + NCHW write (no Y2 buffer)
    ffn2_ln2<<<dim3(625), dim3(512), 0, stream>>>(Y1b, XLb, W2t, bf2, g2, b2, out);
}

// Round 5
// 721.624 us; speedup vs baseline: 1.4304x; 1.0171x over previous
//
#include <hip/hip_runtime.h>
#include <stdint.h>

#define HH 200
#define WW 200
#define HWSZ 40000
#define NPX 80000

typedef __attribute__((ext_vector_type(8))) short bf16x8;
typedef __attribute__((ext_vector_type(4))) float f32x4;

__device__ __forceinline__ float bf2f(unsigned short u) {
    union { uint32_t i; float f; } c; c.i = ((uint32_t)u) << 16; return c.f;
}
__device__ __forceinline__ unsigned short f2bf(float f) {
    union { float f; uint32_t i; } c; c.f = f;
    uint32_t r = c.i + 0x7FFF + ((c.i >> 16) & 1);   // RNE
    return (unsigned short)(r >> 16);
}
__device__ __forceinline__ unsigned int cvtpk_bf16(float lo, float hi) {
    unsigned int r;
    asm("v_cvt_pk_bf16_f32 %0, %1, %2" : "=v"(r) : "v"(lo), "v"(hi));
    return r;
}
// async global->LDS DMA, 16B per lane. LDS dest must be wave-uniform base +
// lane*16 (true for our fragment-order staging). Drained by __syncthreads().
__device__ __forceinline__ void gload16(const void* g, void* l) {
    __builtin_amdgcn_global_load_lds(
        (const __attribute__((address_space(1))) unsigned int*)g,
        (__attribute__((address_space(3))) unsigned int*)l, 16, 0, 0);
}

// ---------------------------------------------------------------------------
// Weight conversion: fp32 -> bf16; W1/W2 transposed to [cout][cin];
// Wcat = concat(Wo, Wr) along k (k<256 -> Wo, k>=256 -> Wr).
// ---------------------------------------------------------------------------
__global__ __launch_bounds__(256) void cvt_weights(
    const float* __restrict__ Wq, const float* __restrict__ Wk,
    const float* __restrict__ Wv, const float* __restrict__ Wo,
    const float* __restrict__ Wr, const float* __restrict__ W1,
    const float* __restrict__ W2,
    unsigned short* Wq_b, unsigned short* Wk_b, unsigned short* Wv_b,
    unsigned short* Wcat, unsigned short* W1t, unsigned short* W2t)
{
    const int seg = blockIdx.y;
    const int idx = blockIdx.x * 256 + threadIdx.x;
    if (seg == 0)      { if (idx < 16384) Wq_b[idx] = f2bf(Wq[idx]); }
    else if (seg == 1) { if (idx < 65536) Wk_b[idx] = f2bf(Wk[idx]); }
    else if (seg == 2) { if (idx < 65536) Wv_b[idx] = f2bf(Wv[idx]); }
    else if (seg == 3) {
        if (idx < 81920) {
            int r = idx / 320, k = idx - r * 320;
            Wcat[idx] = f2bf(k < 256 ? Wo[r * 256 + k] : Wr[r * 64 + (k - 256)]);
        }
    } else if (seg == 4) {
        if (idx < 262144) { int o = idx >> 8, i = idx & 255; W1t[idx] = f2bf(W1[i * 1024 + o]); }
    } else {
        if (idx < 262144) { int o = idx >> 10, i = idx & 1023; W2t[idx] = f2bf(W2[i * 256 + o]); }
    }
}

// ---------------------------------------------------------------------------
// NCHW fp32 -> NHWC bf16 (64px x 64c LDS tile).
// ---------------------------------------------------------------------------
__global__ __launch_bounds__(256) void to_nhwc(
    const float* __restrict__ src, unsigned short* __restrict__ dst, int C)
{
    __shared__ unsigned short T[64][72];
    const int b = blockIdx.z, c0 = blockIdx.y * 64, px0 = blockIdx.x * 64;
    const int t = threadIdx.x;
    const int pxl = t & 63, cl0 = t >> 6;
    const float* sp = src + ((size_t)(b * C + c0 + cl0)) * HWSZ + px0 + pxl;
    #pragma unroll
    for (int i = 0; i < 16; ++i)
        T[pxl][cl0 + i * 4] = f2bf(sp[(size_t)i * 4 * HWSZ]);
    __syncthreads();
    #pragma unroll
    for (int r = 0; r < 2; ++r) {
        int idx = t + r * 256;
        int p = idx >> 3, cof = (idx & 7) * 8;
        uint4 v = *(const uint4*)&T[p][cof];
        *(uint4*)(dst + ((size_t)(b * HWSZ + px0 + p)) * C + c0 + cof) = v;
    }
}

// ---------------------------------------------------------------------------
// bf16 MFMA GEMM (NHWC activations x row-major [cout][cin] weights).
// Out[px][cout] = sum_k In[px][k] * W[cout][k]; M=80000, tile 128x128, BK=32.
// Optional concat second input (k >= K1 -> In2). Out: bf16 (OutB, row stride
// outStride) or fp32 (OutF, stride 256). flags: 1=relu, 2=fp32 accumulate,
// 4=XCD swizzle (bijective m204 remap, y-fastest: the gridDim.y n-blocks of
// one px tile run consecutively on one XCD -> A panel fetched ~once).
// Staging via global_load_lds 16B DMA (LDS dest is lane-contiguous).
// ---------------------------------------------------------------------------
__global__ __launch_bounds__(256) void gemm_bf16(
    const unsigned short* __restrict__ In, int inStride,
    const unsigned short* __restrict__ In2, int in2Stride, int K1,
    const unsigned short* __restrict__ Wb, int wStride, int Ktot,
    unsigned short* __restrict__ OutB, float* __restrict__ OutF,
    const float* __restrict__ bias, int flags, int outStride)
{
    __shared__ bf16x8 AB[1024];   // [0..511] A frags, [512..1023] B frags
    const int t = threadIdx.x;
    int bx = blockIdx.x, by = blockIdx.y;
    if (flags & 4) {
        const int nxy = gridDim.x * gridDim.y;
        const int flat = blockIdx.x + gridDim.x * blockIdx.y;
        const int qq = nxy >> 3, rr = nxy & 7;
        const int xcd = flat & 7, idx = flat >> 3;
        const int w2 = (xcd < rr ? xcd * (qq + 1)
                                 : rr * (qq + 1) + (xcd - rr) * qq) + idx;
        by = w2 % gridDim.y;
        bx = w2 / gridDim.y;
    }
    const int px0 = bx * 128;
    const int n0 = by * 128;
    const int lane = t & 63, w = t >> 6;
    const int mh = w & 1, nh = w >> 1;

    f32x4 acc[4][4] = {};

    for (int k0 = 0; k0 < Ktot; k0 += 32) {
        #pragma unroll
        for (int r = 0; r < 2; ++r) {
            const int c = t + r * 256;
            const int l = c & 63;
            const int ko = k0 + ((l >> 4) << 3);
            {
                const int mt = c >> 6;
                const int px = px0 + mt * 16 + (l & 15);
                const unsigned short* sp = (ko < K1)
                    ? (In  + (size_t)px * inStride  + ko)
                    : (In2 + (size_t)px * in2Stride + (ko - K1));
                gload16(sp, &AB[c]);
            }
            {
                const int nt = c >> 6;
                const int cc = n0 + nt * 16 + (l & 15);
                gload16(Wb + (size_t)cc * wStride + ko, &AB[512 + c]);
            }
        }
        __syncthreads();
        bf16x8 av[4], bv[4];
        #pragma unroll
        for (int i = 0; i < 4; ++i) av[i] = AB[(mh * 4 + i) * 64 + lane];
        #pragma unroll
        for (int j = 0; j < 4; ++j) bv[j] = AB[512 + (nh * 4 + j) * 64 + lane];
        #pragma unroll
        for (int i = 0; i < 4; ++i)
            #pragma unroll
            for (int j = 0; j < 4; ++j)
                acc[i][j] = __builtin_amdgcn_mfma_f32_16x16x32_bf16(
                    av[i], bv[j], acc[i][j], 0, 0, 0);
        __syncthreads();
    }

    const int q = lane >> 4, ln = lane & 15;
    const bool relu = (flags & 1) != 0, accum = (flags & 2) != 0;
    #pragma unroll
    for (int i = 0; i < 4; ++i) {
        #pragma unroll
        for (int j = 0; j < 4; ++j) {
            const int coutv = n0 + nh * 64 + j * 16 + ln;
            const float bval = bias ? bias[coutv] : 0.0f;
            #pragma unroll
            for (int r = 0; r < 4; ++r) {
                const int px = px0 + mh * 64 + i * 16 + q * 4 + r;
                float v = acc[i][j][r] + bval;
                if (relu) v = fmaxf(v, 0.0f);
                if (OutB) {
                    OutB[(size_t)px * outStride + coutv] = f2bf(v);
                } else {
                    float* op = OutF + (size_t)px * 256 + coutv;
                    if (accum) v += *op;
                    *op = v;
                }
            }
        }
    }
}

// ---------------------------------------------------------------------------
// Fused FFN-2nd-half + LN2: Out = LN(XLb + Y1*W2t + bf2) -> NCHW fp32.
// Block = 512 thr (8 waves), tile 128 px x 256 cout (FULL rows), K=1024.
// Staging now via global_load_lds DMA (no VGPR round-trip).
// ---------------------------------------------------------------------------
__global__ __launch_bounds__(512) void ffn2_ln2(
    const unsigned short* __restrict__ Y1,   // [NPX][1024] bf16 (relu'd)
    const unsigned short* __restrict__ XLb,  // [NPX][256]  bf16 residual
    const unsigned short* __restrict__ W2t,  // [256][1024] bf16
    const float* __restrict__ bf2v,          // [256]
    const float* __restrict__ g2, const float* __restrict__ b2,
    float* __restrict__ Out)                 // [2][256][HWSZ] fp32
{
    __shared__ union {
        bf16x8 AB[1536];          // 8 A frags + 16 B frags (24 KB)
        float  T[256 * 33];       // transpose buffer (33.8 KB)
    } sm;
    __shared__ float part_s[4][128], part_q[4][128];

    const int t = threadIdx.x;
    const int px0 = blockIdx.x * 128;
    const int lane = t & 63, w = t >> 6;
    const int mh = w & 1, nh = w >> 1;          // mh: px half, nh: col quarter
    const int q = lane >> 4, ln = lane & 15;

    f32x4 acc[4][4] = {};

    for (int k0 = 0; k0 < 1024; k0 += 32) {
        #pragma unroll
        for (int r = 0; r < 3; ++r) {
            const int c = t + r * 512;           // 0..1535
            const int l = c & 63;
            const int ko = k0 + ((l >> 4) << 3);
            if (c < 512) {                       // A frags: 8 m-tiles
                const int mt = c >> 6;
                const int px = px0 + mt * 16 + (l & 15);
                gload16(Y1 + (size_t)px * 1024 + ko, &sm.AB[c]);
            } else {                             // B frags: 16 n-tiles
                const int c2 = c - 512;
                const int nt = c2 >> 6;
                const int cc = nt * 16 + (l & 15);
                gload16(W2t + (size_t)cc * 1024 + ko, &sm.AB[c]);
            }
        }
        __syncthreads();
        bf16x8 av[4], bv[4];
        #pragma unroll
        for (int i = 0; i < 4; ++i) av[i] = sm.AB[(mh * 4 + i) * 64 + lane];
        #pragma unroll
        for (int j = 0; j < 4; ++j) bv[j] = sm.AB[512 + (nh * 4 + j) * 64 + lane];
        #pragma unroll
        for (int i = 0; i < 4; ++i)
            #pragma unroll
            for (int j = 0; j < 4; ++j)
                acc[i][j] = __builtin_amdgcn_mfma_f32_16x16x32_bf16(
                    av[i], bv[j], acc[i][j], 0, 0, 0);
        __syncthreads();
    }

    // per-column constants
    float biasv[4], gv[4], bvv[4];
    #pragma unroll
    for (int j = 0; j < 4; ++j) {
        const int col = nh * 64 + j * 16 + ln;
        biasv[j] = bf2v[col];
        gv[j] = g2[col];
        bvv[j] = b2[col];
    }

    // residual + partial stats (sum over this wave's 64 cols per pixel)
    #pragma unroll
    for (int i = 0; i < 4; ++i) {
        #pragma unroll
        for (int r = 0; r < 4; ++r) {
            const int pl = mh * 64 + i * 16 + q * 4 + r;
            const size_t px = (size_t)px0 + pl;
            float s = 0.0f, ssq = 0.0f;
            #pragma unroll
            for (int j = 0; j < 4; ++j) {
                const int col = nh * 64 + j * 16 + ln;
                float v = acc[i][j][r] + biasv[j] + bf2f(XLb[px * 256 + col]);
                acc[i][j][r] = v;
                s += v; ssq += v * v;
            }
            #pragma unroll
            for (int o = 1; o <= 8; o <<= 1) {
                s += __shfl_xor(s, o); ssq += __shfl_xor(ssq, o);
            }
            if (ln == 0) { part_s[nh][pl] = s; part_q[nh][pl] = ssq; }
        }
    }
    __syncthreads();

    float muv[4][4], rsv[4][4];
    #pragma unroll
    for (int i = 0; i < 4; ++i) {
        #pragma unroll
        for (int r = 0; r < 4; ++r) {
            const int pl = mh * 64 + i * 16 + q * 4 + r;
            const float s  = part_s[0][pl] + part_s[1][pl] + part_s[2][pl] + part_s[3][pl];
            const float sq = part_q[0][pl] + part_q[1][pl] + part_q[2][pl] + part_q[3][pl];
            const float mu = s * (1.0f / 256.0f);
            muv[i][r] = mu;
            rsv[i][r] = rsqrtf(sq * (1.0f / 256.0f) - mu * mu + 1e-5f);
        }
    }
    __syncthreads();   // done with sm.AB; reuse as sm.T

    // chunked transpose + NCHW write (chunk = 32 pixels)
    #pragma unroll
    for (int ck = 0; ck < 4; ++ck) {
        if (mh == (ck >> 1)) {
            const int ib = (ck & 1) * 2;
            #pragma unroll
            for (int ii = 0; ii < 2; ++ii) {
                const int i = ib + ii;
                #pragma unroll
                for (int j = 0; j < 4; ++j) {
                    const int col = nh * 64 + j * 16 + ln;
                    #pragma unroll
                    for (int r = 0; r < 4; ++r) {
                        sm.T[col * 33 + ii * 16 + q * 4 + r] =
                            (acc[i][j][r] - muv[i][r]) * rsv[i][r] * gv[j] + bvv[j];
                    }
                }
            }
        }
        __syncthreads();
        const int pxc = px0 + ck * 32;          // 32-aligned; 40000%32==0 so
        const int bb = pxc / HWSZ;              // no mid-chunk batch crossing
        const int hw0 = pxc - bb * HWSZ;
        #pragma unroll
        for (int p = 0; p < 16; ++p) {
            const int idx = t + p * 512;
            const int c = idx >> 5, pxl = idx & 31;
            Out[((size_t)(bb * 256 + c)) * HWSZ + hw0 + pxl] = sm.T[c * 33 + pxl];
        }
        __syncthreads();
    }
}

// ---------------------------------------------------------------------------
// 7x7 local-window attention via MFMA, NHWC bf16, replicate pad via clamp.
// This round: XCD-contiguous block swizzle (2704 % 8 == 0 -> simple
// bijective remap), tile-major with all (head,b) of a tile adjacent so
// heads share K/V cache lines and neighbor tiles share halos in L2.
// ---------------------------------------------------------------------------
__global__ __launch_bounds__(256) void attn_bf16(
    const unsigned short* Q, const unsigned short* __restrict__ K,
    const unsigned short* __restrict__ V, unsigned short* A)
{
    __shared__ __align__(16) unsigned short vt[32 * 536];   // 34304 B
    const int flat = blockIdx.x + 169 * (blockIdx.y + 8 * blockIdx.z);
    const int wsz = (flat & 7) * 338 + (flat >> 3);   // 2704/8 = 338
    const int tile = wsz >> 4, rem = wsz & 15;
    const int head = rem >> 1, b = rem & 1;
    const int tiy = tile / 13, tix = tile - tiy * 13;
    const int h0 = tiy * 16, w0 = tix * 16;
    const int t = threadIdx.x;
    const int lane = t & 63, wv = t >> 6;
    const int g = lane >> 4, n = lane & 15;
    const int co = head * 32;
    const size_t pxb = (size_t)b * HWSZ;

    for (int idx = t; idx < 832; idx += 256) {
        if (idx < 704) {
            int ch = idx / 22, r = idx - ch * 22;
            *(unsigned int*)&vt[ch * 536 + r * 24 + 22] = 0u;
        } else {
            int k2 = idx - 704;
            int ch = k2 >> 2, e = k2 & 3;
            *(unsigned int*)&vt[ch * 536 + 528 + e * 2] = 0u;
        }
    }
    for (int idx = t; idx < 484 * 4; idx += 256) {
        int pos = idx >> 2, chunk = idx & 3;
        int r = pos / 22, c = pos - r * 22;
        int gh = min(max(h0 + r - 3, 0), HH - 1);
        int gw = min(max(w0 + c - 3, 0), WW - 1);
        bf16x8 v8 = *(const bf16x8*)(V + (pxb + gh * WW + gw) * 256 + co + chunk * 8);
        unsigned short* dp = &vt[(chunk * 8) * 536 + r * 24 + c];
        #pragma unroll
        for (int e = 0; e < 8; ++e) dp[e * 536] = (unsigned short)v8[e];
    }
    __syncthreads();

    const f32x4 z4 = {0.f, 0.f, 0.f, 0.f};
    const int qw  = min(w0 + n, WW - 1);
    const int kc0 = min(max(w0 - 3 + n, 0), WW - 1);
    const int kc1 = min(w0 + 13 + n, WW - 1);
    const bool hi2 = (g >> 1) != 0;
    const int src0 = ((g & 1) * 2) * 16 + n;
    const int src1 = src0 + 16;

    for (int hh = 0; hh < 4; ++hh) {
        const int hl = wv * 4 + hh;
        const int h = h0 + hl;
        const int hc = min(h, HH - 1);

        const bf16x8 qf = *(const bf16x8*)(Q + (pxb + hc * WW + qw) * 256 + co + g * 8);

        f32x4 s0[7], s1[7];
        #pragma unroll
        for (int i = 0; i < 7; ++i) {
            const int gh = min(max(h - 3 + i, 0), HH - 1);
            const unsigned short* kr = K + (pxb + gh * WW) * 256 + co + g * 8;
            bf16x8 a0 = *(const bf16x8*)(kr + (size_t)kc0 * 256);
            bf16x8 a1 = *(const bf16x8*)(kr + (size_t)kc1 * 256);
            s0[i] = __builtin_amdgcn_mfma_f32_16x16x32_bf16(a0, qf, z4, 0, 0, 0);
            s1[i] = __builtin_amdgcn_mfma_f32_16x16x32_bf16(a1, qf, z4, 0, 0, 0);
        }

        float mx = -3.0e38f;
        #pragma unroll
        for (int r = 0; r < 4; ++r) {
            float m0 = s0[0][r], m1 = s1[0][r];
            #pragma unroll
            for (int i = 1; i < 7; ++i) {
                m0 = fmaxf(m0, s0[i][r]);
                m1 = fmaxf(m1, s1[i][r]);
            }
            const int k0 = 4 * g + r, k1 = k0 + 16;
            mx = fmaxf(mx, ((unsigned)(k0 - n) <= 6u) ? m0 : -3.0e38f);
            mx = fmaxf(mx, ((unsigned)(k1 - n) <= 6u) ? m1 : -3.0e38f);
        }
        mx = fmaxf(mx, __shfl_xor(mx, 16));
        mx = fmaxf(mx, __shfl_xor(mx, 32));

        float sum = 0.0f;
        #pragma unroll
        for (int r = 0; r < 4; ++r) {
            const int k0 = 4 * g + r, k1 = k0 + 16;
            const bool in0 = (unsigned)(k0 - n) <= 6u;
            const bool in1 = (unsigned)(k1 - n) <= 6u;
            #pragma unroll
            for (int i = 0; i < 7; ++i) {
                float e0 = in0 ? __expf((s0[i][r] - mx) * 0.17677669529663687f) : 0.0f;
                float e1 = in1 ? __expf((s1[i][r] - mx) * 0.17677669529663687f) : 0.0f;
                s0[i][r] = e0; s1[i][r] = e1;
                sum += e0 + e1;
            }
        }
        sum += __shfl_xor(sum, 16);
        sum += __shfl_xor(sum, 32);
        const float inv = __builtin_amdgcn_rcpf(sum);

        unsigned int pa[7], pb[7], pc[7], pd[7];
        #pragma unroll
        for (int i = 0; i < 7; ++i) {
            pa[i] = cvtpk_bf16(s0[i][0] * inv, s0[i][1] * inv);
            pb[i] = cvtpk_bf16(s0[i][2] * inv, s0[i][3] * inv);
            pc[i] = cvtpk_bf16(s1[i][0] * inv, s1[i][1] * inv);
            pd[i] = cvtpk_bf16(s1[i][2] * inv, s1[i][3] * inv);
        }

        f32x4 acc0 = z4, acc1 = z4;
        #pragma unroll
        for (int i = 0; i < 7; ++i) {
            const int a0s = __shfl((int)pa[i], src0);
            const int c0s = __shfl((int)pc[i], src0);
            const int b0s = __shfl((int)pb[i], src0);
            const int d0s = __shfl((int)pd[i], src0);
            const int a1s = __shfl((int)pa[i], src1);
            const int c1s = __shfl((int)pc[i], src1);
            const int b1s = __shfl((int)pb[i], src1);
            const int d1s = __shfl((int)pd[i], src1);
            union { unsigned int u[4]; bf16x8 v; } pu;
            pu.u[0] = (unsigned int)(hi2 ? c0s : a0s);
            pu.u[1] = (unsigned int)(hi2 ? d0s : b0s);
            pu.u[2] = (unsigned int)(hi2 ? c1s : a1s);
            pu.u[3] = (unsigned int)(hi2 ? d1s : b1s);
            const unsigned short* vr = &vt[(hl + i) * 24 + g * 8];
            bf16x8 vf0 = *(const bf16x8*)(vr + n * 536);
            bf16x8 vf1 = *(const bf16x8*)(vr + (n + 16) * 536);
            acc0 = __builtin_amdgcn_mfma_f32_16x16x32_bf16(pu.v, vf0, acc0, 0, 0, 0);
            acc1 = __builtin_amdgcn_mfma_f32_16x16x32_bf16(pu.v, vf1, acc1, 0, 0, 0);
        }

        if (h < HH) {
            unsigned short* ap = A + (pxb + h * WW) * 256 + co + n;
            const int wp = w0 + g * 4;
            #pragma unroll
            for (int r = 0; r < 4; ++r) {
                if (wp + r < WW) {
                    ap[(size_t)(wp + r) * 256]      = f2bf(acc0[r]);
                    ap[(size_t)(wp + r) * 256 + 16] = f2bf(acc1[r]);
                }
            }
        }
    }
}

// ---------------------------------------------------------------------------
// LN1: wave-per-pixel over contiguous 256 channels (NHWC fp32 in, bf16 out).
// ---------------------------------------------------------------------------
__global__ __launch_bounds__(256) void ln1_k(
    const float* __restrict__ X, const float* __restrict__ g,
    const float* __restrict__ bt, unsigned short* __restrict__ XLb)
{
    const int wv = threadIdx.x >> 6, lane = threadIdx.x & 63;
    const size_t px = (size_t)blockIdx.x * 4 + wv;
    const float4 v = *(const float4*)(X + px * 256 + lane * 4);
    float s = v.x + v.y + v.z + v.w;
    float ss = v.x * v.x + v.y * v.y + v.z * v.z + v.w * v.w;
    #pragma unroll
    for (int o = 32; o; o >>= 1) { s += __shfl_xor(s, o); ss += __shfl_xor(ss, o); }
    const float mu = s * (1.0f / 256.0f);
    const float var = ss * (1.0f / 256.0f) - mu * mu;
    const float rs = rsqrtf(var + 1e-5f);
    const float4 gv = *(const float4*)(g + lane * 4);
    const float4 bv = *(const float4*)(bt + lane * 4);
    ushort4 o4;
    o4.x = f2bf((v.x - mu) * rs * gv.x + bv.x);
    o4.y = f2bf((v.y - mu) * rs * gv.y + bv.y);
    o4.z = f2bf((v.z - mu) * rs * gv.z + bv.z);
    o4.w = f2bf((v.w - mu) * rs * gv.w + bv.w);
    *(ushort4*)(XLb + px * 256 + lane * 4) = o4;
}

// ---------------------------------------------------------------------------
// Workspace (bytes):                                      total 216.6 MB
//   0         : Fl_bf  [80000][64]  bf16   (10.24 MB)
//   10240000  : Fc_bf  [80000][256] bf16   (40.96)  ┐ after Wcat gemm this
//   51200000  : Qb/Ab  [80000][256] bf16   (40.96)  ├ whole 163.84 MB region
//   92160000  : Kb, Vb [2x 40.96]                   ┘ becomes Y1 [80000][1024]
//   174080000 : XLb    [80000][256] bf16   (40.96)
//   215040000 : bf16 weights (~1.5 MB)
//   d_out     : XW fp32 NHWC scratch (consumed by ln1), then final NCHW out
// ---------------------------------------------------------------------------
extern "C" void kernel_launch(void* const* d_in, const int* in_sizes, int n_in,
                              void* d_out, int out_size, void* d_ws, size_t ws_size,
                              hipStream_t stream)
{
    const float* F_lidar = (const float*)d_in[0];
    const float* F_cam   = (const float*)d_in[1];
    const float* Wq  = (const float*)d_in[2];
    const float* Wk  = (const float*)d_in[3];
    const float* Wv  = (const float*)d_in[4];
    const float* Wo  = (const float*)d_in[5];
    const float* Wr  = (const float*)d_in[6];
    const float* g1  = (const float*)d_in[7];
    const float* b1  = (const float*)d_in[8];
    const float* g2  = (const float*)d_in[9];
    const float* b2  = (const float*)d_in[10];
    const float* W1  = (const float*)d_in[11];
    const float* bf1 = (const float*)d_in[12];
    const float* W2  = (const float*)d_in[13];
    const float* bf2 = (const float*)d_in[14];

    char* wsb = (char*)d_ws;
    unsigned short* Fl  = (unsigned short*)(wsb);
    unsigned short* Fc  = (unsigned short*)(wsb + 10240000);
    unsigned short* Qb  = (unsigned short*)(wsb + 51200000);
    unsigned short* Kb  = (unsigned short*)(wsb + 92160000);
    unsigned short* Vb  = (unsigned short*)(wsb + 133120000);
    unsigned short* Y1b = Fc;                             // [80000][1024] bf16
    unsigned short* XLb = (unsigned short*)(wsb + 174080000);
    unsigned short* Wq_b = (unsigned short*)(wsb + 215040000);
    unsigned short* Wk_b = Wq_b + 16384;
    unsigned short* Wv_b = Wk_b + 65536;
    unsigned short* Wcat = Wv_b + 65536;
    unsigned short* W1t  = Wcat + 81920;
    unsigned short* W2t  = W1t + 262144;
    float* XW  = (float*)d_out;
    float* out = (float*)d_out;

    const dim3 blk(256);

    cvt_weights<<<dim3(1024, 6), blk, 0, stream>>>(Wq, Wk, Wv, Wo, Wr, W1, W2,
        Wq_b, Wk_b, Wv_b, Wcat, W1t, W2t);
    to_nhwc<<<dim3(625, 1, 2), blk, 0, stream>>>(F_lidar, Fl, 64);
    to_nhwc<<<dim3(625, 4, 2), blk, 0, stream>>>(F_cam, Fc, 256);

    // Q/K/V projections (bf16 out); flag 4 = XCD swizzle (A-panel reuse)
    gemm_bf16<<<dim3(625, 2), blk, 0, stream>>>(Fl, 64, Fl, 64, 64,
        Wq_b, 64, 64, Qb, nullptr, nullptr, 4, 256);
    gemm_bf16<<<dim3(625, 2), blk, 0, stream>>>(Fc, 256, Fc, 256, 256,
        Wk_b, 256, 256, Kb, nullptr, nullptr, 4, 256);
    gemm_bf16<<<dim3(625, 2), blk, 0, stream>>>(Fc, 256, Fc, 256, 256,
        Wv_b, 256, 256, Vb, nullptr, nullptr, 4, 256);

    // attention (A overwrites Q in-place; each block touches only its tile)
    attn_bf16<<<dim3(169, 8, 2), blk, 0, stream>>>(Qb, Kb, Vb, Qb);

    // fused out-proj + lidar residual: K=320 concat GEMM -> fp32 XW (d_out)
    gemm_bf16<<<dim3(625, 2), blk, 0, stream>>>(Qb, 256, Fl, 64, 256,
        Wcat, 320, 320, nullptr, XW, nullptr, 4, 256);

    // LN1 -> bf16 XLb
    ln1_k<<<dim3(20000), blk, 0, stream>>>(XW, g1, b1, XLb);

    // FFN half 1: full-width hidden, one dispatch (relu + bias), Y1 bf16
    gemm_bf16<<<dim3(625, 8), blk, 0, stream>>>(XLb, 256, XLb, 256, 256,
        W1t, 256, 256, Y1b, nullptr, bf1, 5, 1024);

    // FFN half 2 fused with residual + LN2 + NCHW write (no Y2 buffer)
    ffn2_ln2<<<dim3(625), dim3(512), 0, stream>>>(Y1b, XLb, W2t, bf2, g2, b2, out);
}

// Round 6
// 693.515 us; speedup vs baseline: 1.4884x; 1.0405x over previous
//
#include <hip/hip_runtime.h>
#include <stdint.h>

#define HH 200
#define WW 200
#define HWSZ 40000
#define NPX 80000

typedef __attribute__((ext_vector_type(8))) short bf16x8;
typedef __attribute__((ext_vector_type(4))) float f32x4;

__device__ __forceinline__ float bf2f(unsigned short u) {
    union { uint32_t i; float f; } c; c.i = ((uint32_t)u) << 16; return c.f;
}
__device__ __forceinline__ unsigned short f2bf(float f) {
    union { float f; uint32_t i; } c; c.f = f;
    uint32_t r = c.i + 0x7FFF + ((c.i >> 16) & 1);   // RNE
    return (unsigned short)(r >> 16);
}
__device__ __forceinline__ unsigned int cvtpk_bf16(float lo, float hi) {
    unsigned int r;
    asm("v_cvt_pk_bf16_f32 %0, %1, %2" : "=v"(r) : "v"(lo), "v"(hi));
    return r;
}
// async global->LDS DMA, 16B per lane. LDS dest must be wave-uniform base +
// lane*16 (true for our fragment-order staging). Drained by __syncthreads().
__device__ __forceinline__ void gload16(const void* g, void* l) {
    __builtin_amdgcn_global_load_lds(
        (const __attribute__((address_space(1))) unsigned int*)g,
        (__attribute__((address_space(3))) unsigned int*)l, 16, 0, 0);
}

// ---------------------------------------------------------------------------
// Weight conversion: fp32 -> bf16; W1/W2 transposed to [cout][cin];
// Wcat = concat(Wo, Wr) along k (k<256 -> Wo, k>=256 -> Wr).
// ---------------------------------------------------------------------------
__global__ __launch_bounds__(256) void cvt_weights(
    const float* __restrict__ Wq, const float* __restrict__ Wk,
    const float* __restrict__ Wv, const float* __restrict__ Wo,
    const float* __restrict__ Wr, const float* __restrict__ W1,
    const float* __restrict__ W2,
    unsigned short* Wq_b, unsigned short* Wk_b, unsigned short* Wv_b,
    unsigned short* Wcat, unsigned short* W1t, unsigned short* W2t)
{
    const int seg = blockIdx.y;
    const int idx = blockIdx.x * 256 + threadIdx.x;
    if (seg == 0)      { if (idx < 16384) Wq_b[idx] = f2bf(Wq[idx]); }
    else if (seg == 1) { if (idx < 65536) Wk_b[idx] = f2bf(Wk[idx]); }
    else if (seg == 2) { if (idx < 65536) Wv_b[idx] = f2bf(Wv[idx]); }
    else if (seg == 3) {
        if (idx < 81920) {
            int r = idx / 320, k = idx - r * 320;
            Wcat[idx] = f2bf(k < 256 ? Wo[r * 256 + k] : Wr[r * 64 + (k - 256)]);
        }
    } else if (seg == 4) {
        if (idx < 262144) { int o = idx >> 8, i = idx & 255; W1t[idx] = f2bf(W1[i * 1024 + o]); }
    } else {
        if (idx < 262144) { int o = idx >> 10, i = idx & 1023; W2t[idx] = f2bf(W2[i * 256 + o]); }
    }
}

// ---------------------------------------------------------------------------
// NCHW fp32 -> NHWC bf16 (64px x 64c LDS tile).
// ---------------------------------------------------------------------------
__global__ __launch_bounds__(256) void to_nhwc(
    const float* __restrict__ src, unsigned short* __restrict__ dst, int C)
{
    __shared__ unsigned short T[64][72];
    const int b = blockIdx.z, c0 = blockIdx.y * 64, px0 = blockIdx.x * 64;
    const int t = threadIdx.x;
    const int pxl = t & 63, cl0 = t >> 6;
    const float* sp = src + ((size_t)(b * C + c0 + cl0)) * HWSZ + px0 + pxl;
    #pragma unroll
    for (int i = 0; i < 16; ++i)
        T[pxl][cl0 + i * 4] = f2bf(sp[(size_t)i * 4 * HWSZ]);
    __syncthreads();
    #pragma unroll
    for (int r = 0; r < 2; ++r) {
        int idx = t + r * 256;
        int p = idx >> 3, cof = (idx & 7) * 8;
        uint4 v = *(const uint4*)&T[p][cof];
        *(uint4*)(dst + ((size_t)(b * HWSZ + px0 + p)) * C + c0 + cof) = v;
    }
}

// ---------------------------------------------------------------------------
// bf16 MFMA GEMM (NHWC activations x row-major [cout][cin] weights).
// Out[px][cout] = sum_k In[px][k] * W[cout][k]; M=80000, tile 128x128, BK=32.
// 2-phase issue-ahead LDS double-buffer: STAGE(k+1) is issued BEFORE the
// ds_read+MFMA of tile k; the single vmcnt(0)+barrier per tile (implicit in
// __syncthreads) then overlaps next-tile HBM latency with current compute.
// flags: 1=relu, 2=fp32 accumulate, 4=XCD swizzle (bijective, y-fastest).
// ---------------------------------------------------------------------------
__global__ __launch_bounds__(256) void gemm_bf16(
    const unsigned short* __restrict__ In, int inStride,
    const unsigned short* __restrict__ In2, int in2Stride, int K1,
    const unsigned short* __restrict__ Wb, int wStride, int Ktot,
    unsigned short* __restrict__ OutB, float* __restrict__ OutF,
    const float* __restrict__ bias, int flags, int outStride)
{
    __shared__ bf16x8 AB[2][1024];   // per buf: [0..511] A, [512..1023] B
    const int t = threadIdx.x;
    int bx = blockIdx.x, by = blockIdx.y;
    if (flags & 4) {
        const int nxy = gridDim.x * gridDim.y;
        const int flat = blockIdx.x + gridDim.x * blockIdx.y;
        const int qq = nxy >> 3, rr = nxy & 7;
        const int xcd = flat & 7, idx = flat >> 3;
        const int w2 = (xcd < rr ? xcd * (qq + 1)
                                 : rr * (qq + 1) + (xcd - rr) * qq) + idx;
        by = w2 % gridDim.y;
        bx = w2 / gridDim.y;
    }
    const int px0 = bx * 128;
    const int n0 = by * 128;
    const int lane = t & 63, w = t >> 6;
    const int mh = w & 1, nh = w >> 1;

    f32x4 acc[4][4] = {};

    auto STAGE = [&](int buf, int k0s) {
        #pragma unroll
        for (int r = 0; r < 2; ++r) {
            const int c = t + r * 256;
            const int l = c & 63;
            const int ko = k0s + ((l >> 4) << 3);
            const int mt = c >> 6;
            {
                const int px = px0 + mt * 16 + (l & 15);
                const unsigned short* sp = (ko < K1)
                    ? (In  + (size_t)px * inStride  + ko)
                    : (In2 + (size_t)px * in2Stride + (ko - K1));
                gload16(sp, &AB[buf][c]);
            }
            {
                const int cc = n0 + mt * 16 + (l & 15);
                gload16(Wb + (size_t)cc * wStride + ko, &AB[buf][512 + c]);
            }
        }
    };

    STAGE(0, 0);
    __syncthreads();
    int cur = 0;

    for (int k0 = 0; k0 < Ktot; k0 += 32) {
        if (k0 + 32 < Ktot) STAGE(cur ^ 1, k0 + 32);   // issue-ahead
        bf16x8 av[4], bv[4];
        #pragma unroll
        for (int i = 0; i < 4; ++i) av[i] = AB[cur][(mh * 4 + i) * 64 + lane];
        #pragma unroll
        for (int j = 0; j < 4; ++j) bv[j] = AB[cur][512 + (nh * 4 + j) * 64 + lane];
        #pragma unroll
        for (int i = 0; i < 4; ++i)
            #pragma unroll
            for (int j = 0; j < 4; ++j)
                acc[i][j] = __builtin_amdgcn_mfma_f32_16x16x32_bf16(
                    av[i], bv[j], acc[i][j], 0, 0, 0);
        __syncthreads();      // drains prefetch, protects buf reuse
        cur ^= 1;
    }

    const int q = lane >> 4, ln = lane & 15;
    const bool relu = (flags & 1) != 0, accum = (flags & 2) != 0;
    #pragma unroll
    for (int i = 0; i < 4; ++i) {
        #pragma unroll
        for (int j = 0; j < 4; ++j) {
            const int coutv = n0 + nh * 64 + j * 16 + ln;
            const float bval = bias ? bias[coutv] : 0.0f;
            #pragma unroll
            for (int r = 0; r < 4; ++r) {
                const int px = px0 + mh * 64 + i * 16 + q * 4 + r;
                float v = acc[i][j][r] + bval;
                if (relu) v = fmaxf(v, 0.0f);
                if (OutB) {
                    OutB[(size_t)px * outStride + coutv] = f2bf(v);
                } else {
                    float* op = OutF + (size_t)px * 256 + coutv;
                    if (accum) v += *op;
                    *op = v;
                }
            }
        }
    }
}

// ---------------------------------------------------------------------------
// Fused FFN-2nd-half + LN2: Out = LN(XLb + Y1*W2t + bf2) -> NCHW fp32.
// Block = 512 thr (8 waves), tile 128 px x 256 cout (FULL rows), K=1024.
// 2-phase issue-ahead double-buffer (see gemm_bf16).
// ---------------------------------------------------------------------------
__global__ __launch_bounds__(512) void ffn2_ln2(
    const unsigned short* __restrict__ Y1,   // [NPX][1024] bf16 (relu'd)
    const unsigned short* __restrict__ XLb,  // [NPX][256]  bf16 residual
    const unsigned short* __restrict__ W2t,  // [256][1024] bf16
    const float* __restrict__ bf2v,          // [256]
    const float* __restrict__ g2, const float* __restrict__ b2,
    float* __restrict__ Out)                 // [2][256][HWSZ] fp32
{
    __shared__ union {
        bf16x8 AB[2][1536];       // 2 x (8 A frags + 16 B frags) = 48 KB
        float  T[256 * 33];       // transpose buffer (33.8 KB)
    } sm;
    __shared__ float part_s[4][128], part_q[4][128];

    const int t = threadIdx.x;
    const int px0 = blockIdx.x * 128;
    const int lane = t & 63, w = t >> 6;
    const int mh = w & 1, nh = w >> 1;          // mh: px half, nh: col quarter
    const int q = lane >> 4, ln = lane & 15;

    f32x4 acc[4][4] = {};

    auto STAGE = [&](int buf, int k0s) {
        #pragma unroll
        for (int r = 0; r < 3; ++r) {
            const int c = t + r * 512;           // 0..1535
            const int l = c & 63;
            const int ko = k0s + ((l >> 4) << 3);
            if (c < 512) {                       // A frags: 8 m-tiles
                const int mt = c >> 6;
                const int px = px0 + mt * 16 + (l & 15);
                gload16(Y1 + (size_t)px * 1024 + ko, &sm.AB[buf][c]);
            } else {                             // B frags: 16 n-tiles
                const int c2 = c - 512;
                const int nt = c2 >> 6;
                const int cc = nt * 16 + (l & 15);
                gload16(W2t + (size_t)cc * 1024 + ko, &sm.AB[buf][c]);
            }
        }
    };

    STAGE(0, 0);
    __syncthreads();
    int cur = 0;

    for (int k0 = 0; k0 < 1024; k0 += 32) {
        if (k0 + 32 < 1024) STAGE(cur ^ 1, k0 + 32);   // issue-ahead
        bf16x8 av[4], bv[4];
        #pragma unroll
        for (int i = 0; i < 4; ++i) av[i] = sm.AB[cur][(mh * 4 + i) * 64 + lane];
        #pragma unroll
        for (int j = 0; j < 4; ++j) bv[j] = sm.AB[cur][512 + (nh * 4 + j) * 64 + lane];
        #pragma unroll
        for (int i = 0; i < 4; ++i)
            #pragma unroll
            for (int j = 0; j < 4; ++j)
                acc[i][j] = __builtin_amdgcn_mfma_f32_16x16x32_bf16(
                    av[i], bv[j], acc[i][j], 0, 0, 0);
        __syncthreads();
        cur ^= 1;
    }

    // per-column constants
    float biasv[4], gv[4], bvv[4];
    #pragma unroll
    for (int j = 0; j < 4; ++j) {
        const int col = nh * 64 + j * 16 + ln;
        biasv[j] = bf2v[col];
        gv[j] = g2[col];
        bvv[j] = b2[col];
    }

    // residual + partial stats (sum over this wave's 64 cols per pixel)
    #pragma unroll
    for (int i = 0; i < 4; ++i) {
        #pragma unroll
        for (int r = 0; r < 4; ++r) {
            const int pl = mh * 64 + i * 16 + q * 4 + r;
            const size_t px = (size_t)px0 + pl;
            float s = 0.0f, ssq = 0.0f;
            #pragma unroll
            for (int j = 0; j < 4; ++j) {
                const int col = nh * 64 + j * 16 + ln;
                float v = acc[i][j][r] + biasv[j] + bf2f(XLb[px * 256 + col]);
                acc[i][j][r] = v;
                s += v; ssq += v * v;
            }
            #pragma unroll
            for (int o = 1; o <= 8; o <<= 1) {
                s += __shfl_xor(s, o); ssq += __shfl_xor(ssq, o);
            }
            if (ln == 0) { part_s[nh][pl] = s; part_q[nh][pl] = ssq; }
        }
    }
    __syncthreads();

    float muv[4][4], rsv[4][4];
    #pragma unroll
    for (int i = 0; i < 4; ++i) {
        #pragma unroll
        for (int r = 0; r < 4; ++r) {
            const int pl = mh * 64 + i * 16 + q * 4 + r;
            const float s  = part_s[0][pl] + part_s[1][pl] + part_s[2][pl] + part_s[3][pl];
            const float sq = part_q[0][pl] + part_q[1][pl] + part_q[2][pl] + part_q[3][pl];
            const float mu = s * (1.0f / 256.0f);
            muv[i][r] = mu;
            rsv[i][r] = rsqrtf(sq * (1.0f / 256.0f) - mu * mu + 1e-5f);
        }
    }
    __syncthreads();   // done with sm.AB; reuse as sm.T

    // chunked transpose + NCHW write (chunk = 32 pixels)
    #pragma unroll
    for (int ck = 0; ck < 4; ++ck) {
        if (mh == (ck >> 1)) {
            const int ib = (ck & 1) * 2;
            #pragma unroll
            for (int ii = 0; ii < 2; ++ii) {
                const int i = ib + ii;
                #pragma unroll
                for (int j = 0; j < 4; ++j) {
                    const int col = nh * 64 + j * 16 + ln;
                    #pragma unroll
                    for (int r = 0; r < 4; ++r) {
                        sm.T[col * 33 + ii * 16 + q * 4 + r] =
                            (acc[i][j][r] - muv[i][r]) * rsv[i][r] * gv[j] + bvv[j];
                    }
                }
            }
        }
        __syncthreads();
        const int pxc = px0 + ck * 32;          // 32-aligned; 40000%32==0 so
        const int bb = pxc / HWSZ;              // no mid-chunk batch crossing
        const int hw0 = pxc - bb * HWSZ;
        #pragma unroll
        for (int p = 0; p < 16; ++p) {
            const int idx = t + p * 512;
            const int c = idx >> 5, pxl = idx & 31;
            Out[((size_t)(bb * 256 + c)) * HWSZ + hw0 + pxl] = sm.T[c * 33 + pxl];
        }
        __syncthreads();
    }
}

// ---------------------------------------------------------------------------
// 7x7 local-window attention via MFMA, NHWC bf16, replicate pad via clamp.
// (unchanged this round; XCD-contiguous swizzle from round 5 kept)
// ---------------------------------------------------------------------------
__global__ __launch_bounds__(256) void attn_bf16(
    const unsigned short* Q, const unsigned short* __restrict__ K,
    const unsigned short* __restrict__ V, unsigned short* A)
{
    __shared__ __align__(16) unsigned short vt[32 * 536];   // 34304 B
    const int flat = blockIdx.x + 169 * (blockIdx.y + 8 * blockIdx.z);
    const int wsz = (flat & 7) * 338 + (flat >> 3);   // 2704/8 = 338
    const int tile = wsz >> 4, rem = wsz & 15;
    const int head = rem >> 1, b = rem & 1;
    const int tiy = tile / 13, tix = tile - tiy * 13;
    const int h0 = tiy * 16, w0 = tix * 16;
    const int t = threadIdx.x;
    const int lane = t & 63, wv = t >> 6;
    const int g = lane >> 4, n = lane & 15;
    const int co = head * 32;
    const size_t pxb = (size_t)b * HWSZ;

    for (int idx = t; idx < 832; idx += 256) {
        if (idx < 704) {
            int ch = idx / 22, r = idx - ch * 22;
            *(unsigned int*)&vt[ch * 536 + r * 24 + 22] = 0u;
        } else {
            int k2 = idx - 704;
            int ch = k2 >> 2, e = k2 & 3;
            *(unsigned int*)&vt[ch * 536 + 528 + e * 2] = 0u;
        }
    }
    for (int idx = t; idx < 484 * 4; idx += 256) {
        int pos = idx >> 2, chunk = idx & 3;
        int r = pos / 22, c = pos - r * 22;
        int gh = min(max(h0 + r - 3, 0), HH - 1);
        int gw = min(max(w0 + c - 3, 0), WW - 1);
        bf16x8 v8 = *(const bf16x8*)(V + (pxb + gh * WW + gw) * 256 + co + chunk * 8);
        unsigned short* dp = &vt[(chunk * 8) * 536 + r * 24 + c];
        #pragma unroll
        for (int e = 0; e < 8; ++e) dp[e * 536] = (unsigned short)v8[e];
    }
    __syncthreads();

    const f32x4 z4 = {0.f, 0.f, 0.f, 0.f};
    const int qw  = min(w0 + n, WW - 1);
    const int kc0 = min(max(w0 - 3 + n, 0), WW - 1);
    const int kc1 = min(w0 + 13 + n, WW - 1);
    const bool hi2 = (g >> 1) != 0;
    const int src0 = ((g & 1) * 2) * 16 + n;
    const int src1 = src0 + 16;

    for (int hh = 0; hh < 4; ++hh) {
        const int hl = wv * 4 + hh;
        const int h = h0 + hl;
        const int hc = min(h, HH - 1);

        const bf16x8 qf = *(const bf16x8*)(Q + (pxb + hc * WW + qw) * 256 + co + g * 8);

        f32x4 s0[7], s1[7];
        #pragma unroll
        for (int i = 0; i < 7; ++i) {
            const int gh = min(max(h - 3 + i, 0), HH - 1);
            const unsigned short* kr = K + (pxb + gh * WW) * 256 + co + g * 8;
            bf16x8 a0 = *(const bf16x8*)(kr + (size_t)kc0 * 256);
            bf16x8 a1 = *(const bf16x8*)(kr + (size_t)kc1 * 256);
            s0[i] = __builtin_amdgcn_mfma_f32_16x16x32_bf16(a0, qf, z4, 0, 0, 0);
            s1[i] = __builtin_amdgcn_mfma_f32_16x16x32_bf16(a1, qf, z4, 0, 0, 0);
        }

        float mx = -3.0e38f;
        #pragma unroll
        for (int r = 0; r < 4; ++r) {
            float m0 = s0[0][r], m1 = s1[0][r];
            #pragma unroll
            for (int i = 1; i < 7; ++i) {
                m0 = fmaxf(m0, s0[i][r]);
                m1 = fmaxf(m1, s1[i][r]);
            }
            const int k0 = 4 * g + r, k1 = k0 + 16;
            mx = fmaxf(mx, ((unsigned)(k0 - n) <= 6u) ? m0 : -3.0e38f);
            mx = fmaxf(mx, ((unsigned)(k1 - n) <= 6u) ? m1 : -3.0e38f);
        }
        mx = fmaxf(mx, __shfl_xor(mx, 16));
        mx = fmaxf(mx, __shfl_xor(mx, 32));

        float sum = 0.0f;
        #pragma unroll
        for (int r = 0; r < 4; ++r) {
            const int k0 = 4 * g + r, k1 = k0 + 16;
            const bool in0 = (unsigned)(k0 - n) <= 6u;
            const bool in1 = (unsigned)(k1 - n) <= 6u;
            #pragma unroll
            for (int i = 0; i < 7; ++i) {
                float e0 = in0 ? __expf((s0[i][r] - mx) * 0.17677669529663687f) : 0.0f;
                float e1 = in1 ? __expf((s1[i][r] - mx) * 0.17677669529663687f) : 0.0f;
                s0[i][r] = e0; s1[i][r] = e1;
                sum += e0 + e1;
            }
        }
        sum += __shfl_xor(sum, 16);
        sum += __shfl_xor(sum, 32);
        const float inv = __builtin_amdgcn_rcpf(sum);

        unsigned int pa[7], pb[7], pc[7], pd[7];
        #pragma unroll
        for (int i = 0; i < 7; ++i) {
            pa[i] = cvtpk_bf16(s0[i][0] * inv, s0[i][1] * inv);
            pb[i] = cvtpk_bf16(s0[i][2] * inv, s0[i][3] * inv);
            pc[i] = cvtpk_bf16(s1[i][0] * inv, s1[i][1] * inv);
            pd[i] = cvtpk_bf16(s1[i][2] * inv, s1[i][3] * inv);
        }

        f32x4 acc0 = z4, acc1 = z4;
        #pragma unroll
        for (int i = 0; i < 7; ++i) {
            const int a0s = __shfl((int)pa[i], src0);
            const int c0s = __shfl((int)pc[i], src0);
            const int b0s = __shfl((int)pb[i], src0);
            const int d0s = __shfl((int)pd[i], src0);
            const int a1s = __shfl((int)pa[i], src1);
            const int c1s = __shfl((int)pc[i], src1);
            const int b1s = __shfl((int)pb[i], src1);
            const int d1s = __shfl((int)pd[i], src1);
            union { unsigned int u[4]; bf16x8 v; } pu;
            pu.u[0] = (unsigned int)(hi2 ? c0s : a0s);
            pu.u[1] = (unsigned int)(hi2 ? d0s : b0s);
            pu.u[2] = (unsigned int)(hi2 ? c1s : a1s);
            pu.u[3] = (unsigned int)(hi2 ? d1s : b1s);
            const unsigned short* vr = &vt[(hl + i) * 24 + g * 8];
            bf16x8 vf0 = *(const bf16x8*)(vr + n * 536);
            bf16x8 vf1 = *(const bf16x8*)(vr + (n + 16) * 536);
            acc0 = __builtin_amdgcn_mfma_f32_16x16x32_bf16(pu.v, vf0, acc0, 0, 0, 0);
            acc1 = __builtin_amdgcn_mfma_f32_16x16x32_bf16(pu.v, vf1, acc1, 0, 0, 0);
        }

        if (h < HH) {
            unsigned short* ap = A + (pxb + h * WW) * 256 + co + n;
            const int wp = w0 + g * 4;
            #pragma unroll
            for (int r = 0; r < 4; ++r) {
                if (wp + r < WW) {
                    ap[(size_t)(wp + r) * 256]      = f2bf(acc0[r]);
                    ap[(size_t)(wp + r) * 256 + 16] = f2bf(acc1[r]);
                }
            }
        }
    }
}

// ---------------------------------------------------------------------------
// LN1: wave-per-pixel over contiguous 256 channels (NHWC fp32 in, bf16 out).
// ---------------------------------------------------------------------------
__global__ __launch_bounds__(256) void ln1_k(
    const float* __restrict__ X, const float* __restrict__ g,
    const float* __restrict__ bt, unsigned short* __restrict__ XLb)
{
    const int wv = threadIdx.x >> 6, lane = threadIdx.x & 63;
    const size_t px = (size_t)blockIdx.x * 4 + wv;
    const float4 v = *(const float4*)(X + px * 256 + lane * 4);
    float s = v.x + v.y + v.z + v.w;
    float ss = v.x * v.x + v.y * v.y + v.z * v.z + v.w * v.w;
    #pragma unroll
    for (int o = 32; o; o >>= 1) { s += __shfl_xor(s, o); ss += __shfl_xor(ss, o); }
    const float mu = s * (1.0f / 256.0f);
    const float var = ss * (1.0f / 256.0f) - mu * mu;
    const float rs = rsqrtf(var + 1e-5f);
    const float4 gv = *(const float4*)(g + lane * 4);
    const float4 bv = *(const float4*)(bt + lane * 4);
    ushort4 o4;
    o4.x = f2bf((v.x - mu) * rs * gv.x + bv.x);
    o4.y = f2bf((v.y - mu) * rs * gv.y + bv.y);
    o4.z = f2bf((v.z - mu) * rs * gv.z + bv.z);
    o4.w = f2bf((v.w - mu) * rs * gv.w + bv.w);
    *(ushort4*)(XLb + px * 256 + lane * 4) = o4;
}

// ---------------------------------------------------------------------------
// Workspace (bytes):                                      total 216.6 MB
//   0         : Fl_bf  [80000][64]  bf16   (10.24 MB)
//   10240000  : Fc_bf  [80000][256] bf16   (40.96)  ┐ after Wcat gemm this
//   51200000  : Qb/Ab  [80000][256] bf16   (40.96)  ├ whole 163.84 MB region
//   92160000  : Kb, Vb [2x 40.96]                   ┘ becomes Y1 [80000][1024]
//   174080000 : XLb    [80000][256] bf16   (40.96)
//   215040000 : bf16 weights (~1.5 MB)
//   d_out     : XW fp32 NHWC scratch (consumed by ln1), then final NCHW out
// ---------------------------------------------------------------------------
extern "C" void kernel_launch(void* const* d_in, const int* in_sizes, int n_in,
                              void* d_out, int out_size, void* d_ws, size_t ws_size,
                              hipStream_t stream)
{
    const float* F_lidar = (const float*)d_in[0];
    const float* F_cam   = (const float*)d_in[1];
    const float* Wq  = (const float*)d_in[2];
    const float* Wk  = (const float*)d_in[3];
    const float* Wv  = (const float*)d_in[4];
    const float* Wo  = (const float*)d_in[5];
    const float* Wr  = (const float*)d_in[6];
    const float* g1  = (const float*)d_in[7];
    const float* b1  = (const float*)d_in[8];
    const float* g2  = (const float*)d_in[9];
    const float* b2  = (const float*)d_in[10];
    const float* W1  = (const float*)d_in[11];
    const float* bf1 = (const float*)d_in[12];
    const float* W2  = (const float*)d_in[13];
    const float* bf2 = (const float*)d_in[14];

    char* wsb = (char*)d_ws;
    unsigned short* Fl  = (unsigned short*)(wsb);
    unsigned short* Fc  = (unsigned short*)(wsb + 10240000);
    unsigned short* Qb  = (unsigned short*)(wsb + 51200000);
    unsigned short* Kb  = (unsigned short*)(wsb + 92160000);
    unsigned short* Vb  = (unsigned short*)(wsb + 133120000);
    unsigned short* Y1b = Fc;                             // [80000][1024] bf16
    unsigned short* XLb = (unsigned short*)(wsb + 174080000);
    unsigned short* Wq_b = (unsigned short*)(wsb + 215040000);
    unsigned short* Wk_b = Wq_b + 16384;
    unsigned short* Wv_b = Wk_b + 65536;
    unsigned short* Wcat = Wv_b + 65536;
    unsigned short* W1t  = Wcat + 81920;
    unsigned short* W2t  = W1t + 262144;
    float* XW  = (float*)d_out;
    float* out = (float*)d_out;

    const dim3 blk(256);

    cvt_weights<<<dim3(1024, 6), blk, 0, stream>>>(Wq, Wk, Wv, Wo, Wr, W1, W2,
        Wq_b, Wk_b, Wv_b, Wcat, W1t, W2t);
    to_nhwc<<<dim3(625, 1, 2), blk, 0, stream>>>(F_lidar, Fl, 64);
    to_nhwc<<<dim3(625, 4, 2), blk, 0, stream>>>(F_cam, Fc, 256);

    // Q/K/V projections (bf16 out); flag 4 = XCD swizzle (A-panel reuse)
    gemm_bf16<<<dim3(625, 2), blk, 0, stream>>>(Fl, 64, Fl, 64, 64,
        Wq_b, 64, 64, Qb, nullptr, nullptr, 4, 256);
    gemm_bf16<<<dim3(625, 2), blk, 0, stream>>>(Fc, 256, Fc, 256, 256,
        Wk_b, 256, 256, Kb, nullptr, nullptr, 4, 256);
    gemm_bf16<<<dim3(625, 2), blk, 0, stream>>>(Fc, 256, Fc, 256, 256,
        Wv_b, 256, 256, Vb, nullptr, nullptr, 4, 256);

    // attention (A overwrites Q in-place; each block touches only its tile)
    attn_bf16<<<dim3(169, 8, 2), blk, 0, stream>>>(Qb, Kb, Vb, Qb);

    // fused out-proj + lidar residual: K=320 concat GEMM -> fp32 XW (d_out)
    gemm_bf16<<<dim3(625, 2), blk, 0, stream>>>(Qb, 256, Fl, 64, 256,
        Wcat, 320, 320, nullptr, XW, nullptr, 4, 256);

    // LN1 -> bf16 XLb
    ln1_k<<<dim3(20000), blk, 0, stream>>>(XW, g1, b1, XLb);

    // FFN half 1: full-width hidden, one dispatch (relu + bias), Y1 bf16
    gemm_bf16<<<dim3(625, 8), blk, 0, stream>>>(XLb, 256, XLb, 256, 256,
        W1t, 256, 256, Y1b, nullptr, bf1, 5, 1024);

    // FFN half 2 fused with residual + LN2 + NCHW write (no Y2 buffer)
    ffn2_ln2<<<dim3(625), dim3(512), 0, stream>>>(Y1b, XLb, W2t, bf2, g2, b2, out);
}

// Round 8
// 682.526 us; speedup vs baseline: 1.5123x; 1.0161x over previous
//
#include <hip/hip_runtime.h>
#include <stdint.h>

#define HH 200
#define WW 200
#define HWSZ 40000
#define NPX 80000

typedef __attribute__((ext_vector_type(8))) short bf16x8;
typedef __attribute__((ext_vector_type(4))) float f32x4;

// counted waits with "memory" clobber (no implicit vmcnt(0) drain, unlike
// __syncthreads); barrier via the builtin so the compiler models it.
#define VM_WAIT(N) asm volatile("s_waitcnt vmcnt(" #N ")" ::: "memory")
#define LGKM_WAIT0 asm volatile("s_waitcnt lgkmcnt(0)" ::: "memory")
#define BARRIER()  __builtin_amdgcn_s_barrier()
#define SCHED_FENCE() __builtin_amdgcn_sched_barrier(0)

__device__ __forceinline__ float bf2f(unsigned short u) {
    union { uint32_t i; float f; } c; c.i = ((uint32_t)u) << 16; return c.f;
}
__device__ __forceinline__ unsigned short f2bf(float f) {
    union { float f; uint32_t i; } c; c.f = f;
    uint32_t r = c.i + 0x7FFF + ((c.i >> 16) & 1);   // RNE
    return (unsigned short)(r >> 16);
}
__device__ __forceinline__ unsigned int cvtpk_bf16(float lo, float hi) {
    unsigned int r;
    asm("v_cvt_pk_bf16_f32 %0, %1, %2" : "=v"(r) : "v"(lo), "v"(hi));
    return r;
}
// async global->LDS DMA, 16B per lane. LDS dest must be wave-uniform base +
// lane*16 (true for our fragment-order staging).
__device__ __forceinline__ void gload16(const void* g, void* l) {
    __builtin_amdgcn_global_load_lds(
        (const __attribute__((address_space(1))) unsigned int*)g,
        (__attribute__((address_space(3))) unsigned int*)l, 16, 0, 0);
}

// ---------------------------------------------------------------------------
// Weight conversion: fp32 -> bf16; W1/W2 transposed to [cout][cin];
// Wcat = concat(Wo, Wr) along k (k<256 -> Wo, k>=256 -> Wr).
// ---------------------------------------------------------------------------
__global__ __launch_bounds__(256) void cvt_weights(
    const float* __restrict__ Wq, const float* __restrict__ Wk,
    const float* __restrict__ Wv, const float* __restrict__ Wo,
    const float* __restrict__ Wr, const float* __restrict__ W1,
    const float* __restrict__ W2,
    unsigned short* Wq_b, unsigned short* Wk_b, unsigned short* Wv_b,
    unsigned short* Wcat, unsigned short* W1t, unsigned short* W2t)
{
    const int seg = blockIdx.y;
    const int idx = blockIdx.x * 256 + threadIdx.x;
    if (seg == 0)      { if (idx < 16384) Wq_b[idx] = f2bf(Wq[idx]); }
    else if (seg == 1) { if (idx < 65536) Wk_b[idx] = f2bf(Wk[idx]); }
    else if (seg == 2) { if (idx < 65536) Wv_b[idx] = f2bf(Wv[idx]); }
    else if (seg == 3) {
        if (idx < 81920) {
            int r = idx / 320, k = idx - r * 320;
            Wcat[idx] = f2bf(k < 256 ? Wo[r * 256 + k] : Wr[r * 64 + (k - 256)]);
        }
    } else if (seg == 4) {
        if (idx < 262144) { int o = idx >> 8, i = idx & 255; W1t[idx] = f2bf(W1[i * 1024 + o]); }
    } else {
        if (idx < 262144) { int o = idx >> 10, i = idx & 1023; W2t[idx] = f2bf(W2[i * 256 + o]); }
    }
}

// ---------------------------------------------------------------------------
// NCHW fp32 -> NHWC bf16 (64px x 64c LDS tile).
// ---------------------------------------------------------------------------
__global__ __launch_bounds__(256) void to_nhwc(
    const float* __restrict__ src, unsigned short* __restrict__ dst, int C)
{
    __shared__ unsigned short T[64][72];
    const int b = blockIdx.z, c0 = blockIdx.y * 64, px0 = blockIdx.x * 64;
    const int t = threadIdx.x;
    const int pxl = t & 63, cl0 = t >> 6;
    const float* sp = src + ((size_t)(b * C + c0 + cl0)) * HWSZ + px0 + pxl;
    #pragma unroll
    for (int i = 0; i < 16; ++i)
        T[pxl][cl0 + i * 4] = f2bf(sp[(size_t)i * 4 * HWSZ]);
    __syncthreads();
    #pragma unroll
    for (int r = 0; r < 2; ++r) {
        int idx = t + r * 256;
        int p = idx >> 3, cof = (idx & 7) * 8;
        uint4 v = *(const uint4*)&T[p][cof];
        *(uint4*)(dst + ((size_t)(b * HWSZ + px0 + p)) * C + c0 + cof) = v;
    }
}

// ---------------------------------------------------------------------------
// bf16 MFMA GEMM (NHWC activations x row-major [cout][cin] weights).
// Out[px][cout] = sum_k In[px][k] * W[cout][k]; M=80000, tile 128x128, BK=32.
// Counted-vmcnt K-loop (T4): 2 tiles in flight, wait vmcnt(4) per iter
// (4 = DMA instrs/tile/wave) -- next tile's loads never drained in steady
// state. lgkmcnt(0)+barrier before buffer overwrite kills the WAR race.
// flags: 1=relu, 2=fp32 accumulate, 4=XCD swizzle (bijective, y-fastest).
// ---------------------------------------------------------------------------
__global__ __launch_bounds__(256) void gemm_bf16(
    const unsigned short* __restrict__ In, int inStride,
    const unsigned short* __restrict__ In2, int in2Stride, int K1,
    const unsigned short* __restrict__ Wb, int wStride, int Ktot,
    unsigned short* __restrict__ OutB, float* __restrict__ OutF,
    const float* __restrict__ bias, int flags, int outStride)
{
    __shared__ bf16x8 AB[2][1024];   // per buf: [0..511] A, [512..1023] B
    const int t = threadIdx.x;
    int bx = blockIdx.x, by = blockIdx.y;
    if (flags & 4) {
        const int nxy = gridDim.x * gridDim.y;
        const int flat = blockIdx.x + gridDim.x * blockIdx.y;
        const int qq = nxy >> 3, rr = nxy & 7;
        const int xcd = flat & 7, idx = flat >> 3;
        const int w2 = (xcd < rr ? xcd * (qq + 1)
                                 : rr * (qq + 1) + (xcd - rr) * qq) + idx;
        by = w2 % gridDim.y;
        bx = w2 / gridDim.y;
    }
    const int px0 = bx * 128;
    const int n0 = by * 128;
    const int lane = t & 63, w = t >> 6;
    const int mh = w & 1, nh = w >> 1;

    f32x4 acc[4][4] = {};

    auto STAGE = [&](int buf, int k0s) {   // 4 gload16 per thread
        #pragma unroll
        for (int r = 0; r < 2; ++r) {
            const int c = t + r * 256;
            const int l = c & 63;
            const int ko = k0s + ((l >> 4) << 3);
            const int mt = c >> 6;
            {
                const int px = px0 + mt * 16 + (l & 15);
                const unsigned short* sp = (ko < K1)
                    ? (In  + (size_t)px * inStride  + ko)
                    : (In2 + (size_t)px * in2Stride + (ko - K1));
                gload16(sp, &AB[buf][c]);
            }
            {
                const int cc = n0 + mt * 16 + (l & 15);
                gload16(Wb + (size_t)cc * wStride + ko, &AB[buf][512 + c]);
            }
        }
    };

    const int nsteps = Ktot >> 5;
    STAGE(0, 0);
    if (nsteps > 1) STAGE(1, 32);
    int cur = 0;

    for (int s = 0; s < nsteps - 1; ++s) {
        VM_WAIT(4);          // tile s landed (s+1 still in flight)
        BARRIER();
        bf16x8 av[4], bv[4];
        #pragma unroll
        for (int i = 0; i < 4; ++i) av[i] = AB[cur][(mh * 4 + i) * 64 + lane];
        #pragma unroll
        for (int j = 0; j < 4; ++j) bv[j] = AB[cur][512 + (nh * 4 + j) * 64 + lane];
        LGKM_WAIT0;          // frag reads complete before buffer reuse
        BARRIER();
        SCHED_FENCE();
        if (s + 2 < nsteps) STAGE(cur, (s + 2) * 32);
        #pragma unroll
        for (int i = 0; i < 4; ++i)
            #pragma unroll
            for (int j = 0; j < 4; ++j)
                acc[i][j] = __builtin_amdgcn_mfma_f32_16x16x32_bf16(
                    av[i], bv[j], acc[i][j], 0, 0, 0);
        cur ^= 1;
    }
    VM_WAIT(0);
    BARRIER();
    {
        bf16x8 av[4], bv[4];
        #pragma unroll
        for (int i = 0; i < 4; ++i) av[i] = AB[cur][(mh * 4 + i) * 64 + lane];
        #pragma unroll
        for (int j = 0; j < 4; ++j) bv[j] = AB[cur][512 + (nh * 4 + j) * 64 + lane];
        #pragma unroll
        for (int i = 0; i < 4; ++i)
            #pragma unroll
            for (int j = 0; j < 4; ++j)
                acc[i][j] = __builtin_amdgcn_mfma_f32_16x16x32_bf16(
                    av[i], bv[j], acc[i][j], 0, 0, 0);
    }

    const int q = lane >> 4, ln = lane & 15;
    const bool relu = (flags & 1) != 0, accum = (flags & 2) != 0;
    #pragma unroll
    for (int i = 0; i < 4; ++i) {
        #pragma unroll
        for (int j = 0; j < 4; ++j) {
            const int coutv = n0 + nh * 64 + j * 16 + ln;
            const float bval = bias ? bias[coutv] : 0.0f;
            #pragma unroll
            for (int r = 0; r < 4; ++r) {
                const int px = px0 + mh * 64 + i * 16 + q * 4 + r;
                float v = acc[i][j][r] + bval;
                if (relu) v = fmaxf(v, 0.0f);
                if (OutB) {
                    OutB[(size_t)px * outStride + coutv] = f2bf(v);
                } else {
                    float* op = OutF + (size_t)px * 256 + coutv;
                    if (accum) v += *op;
                    *op = v;
                }
            }
        }
    }
}

// ---------------------------------------------------------------------------
// Fused FFN-2nd-half + LN2: Out = LN(XLb + Y1*W2t + bf2) -> NCHW fp32.
// Block = 512 thr (8 waves), tile 128 px x 256 cout (FULL rows), K=1024.
// Counted-vmcnt K-loop (3 DMA instrs/tile/wave -> vmcnt(3)).
// ---------------------------------------------------------------------------
__global__ __launch_bounds__(512) void ffn2_ln2(
    const unsigned short* __restrict__ Y1,   // [NPX][1024] bf16 (relu'd)
    const unsigned short* __restrict__ XLb,  // [NPX][256]  bf16 residual
    const unsigned short* __restrict__ W2t,  // [256][1024] bf16
    const float* __restrict__ bf2v,          // [256]
    const float* __restrict__ g2, const float* __restrict__ b2,
    float* __restrict__ Out)                 // [2][256][HWSZ] fp32
{
    __shared__ union {
        bf16x8 AB[2][1536];       // 2 x (8 A frags + 16 B frags) = 48 KB
        float  T[256 * 33];       // transpose buffer (33.8 KB)
    } sm;
    __shared__ float part_s[4][128], part_q[4][128];

    const int t = threadIdx.x;
    const int px0 = blockIdx.x * 128;
    const int lane = t & 63, w = t >> 6;
    const int mh = w & 1, nh = w >> 1;          // mh: px half, nh: col quarter
    const int q = lane >> 4, ln = lane & 15;

    // per-column constants loaded BEFORE the K-loop so no stray VMEM
    // perturbs the counted vmcnt levels inside it.
    float biasv[4], gv[4], bvv[4];
    #pragma unroll
    for (int j = 0; j < 4; ++j) {
        const int col = nh * 64 + j * 16 + ln;
        biasv[j] = bf2v[col];
        gv[j] = g2[col];
        bvv[j] = b2[col];
    }

    f32x4 acc[4][4] = {};

    auto STAGE = [&](int buf, int k0s) {   // 3 gload16 per thread
        #pragma unroll
        for (int r = 0; r < 3; ++r) {
            const int c = t + r * 512;           // 0..1535
            const int l = c & 63;
            const int ko = k0s + ((l >> 4) << 3);
            if (c < 512) {                       // A frags: 8 m-tiles
                const int mt = c >> 6;
                const int px = px0 + mt * 16 + (l & 15);
                gload16(Y1 + (size_t)px * 1024 + ko, &sm.AB[buf][c]);
            } else {                             // B frags: 16 n-tiles
                const int c2 = c - 512;
                const int nt = c2 >> 6;
                const int cc = nt * 16 + (l & 15);
                gload16(W2t + (size_t)cc * 1024 + ko, &sm.AB[buf][c]);
            }
        }
    };

    STAGE(0, 0);
    STAGE(1, 32);
    int cur = 0;

    for (int s = 0; s < 31; ++s) {
        VM_WAIT(3);          // tile s landed (s+1 still in flight)
        BARRIER();
        bf16x8 av[4], bv[4];
        #pragma unroll
        for (int i = 0; i < 4; ++i) av[i] = sm.AB[cur][(mh * 4 + i) * 64 + lane];
        #pragma unroll
        for (int j = 0; j < 4; ++j) bv[j] = sm.AB[cur][512 + (nh * 4 + j) * 64 + lane];
        LGKM_WAIT0;
        BARRIER();
        SCHED_FENCE();
        if (s + 2 < 32) STAGE(cur, (s + 2) * 32);
        #pragma unroll
        for (int i = 0; i < 4; ++i)
            #pragma unroll
            for (int j = 0; j < 4; ++j)
                acc[i][j] = __builtin_amdgcn_mfma_f32_16x16x32_bf16(
                    av[i], bv[j], acc[i][j], 0, 0, 0);
        cur ^= 1;
    }
    VM_WAIT(0);
    BARRIER();
    {
        bf16x8 av[4], bv[4];
        #pragma unroll
        for (int i = 0; i < 4; ++i) av[i] = sm.AB[cur][(mh * 4 + i) * 64 + lane];
        #pragma unroll
        for (int j = 0; j < 4; ++j) bv[j] = sm.AB[cur][512 + (nh * 4 + j) * 64 + lane];
        #pragma unroll
        for (int i = 0; i < 4; ++i)
            #pragma unroll
            for (int j = 0; j < 4; ++j)
                acc[i][j] = __builtin_amdgcn_mfma_f32_16x16x32_bf16(
                    av[i], bv[j], acc[i][j], 0, 0, 0);
    }

    // residual + partial stats (sum over this wave's 64 cols per pixel)
    #pragma unroll
    for (int i = 0; i < 4; ++i) {
        #pragma unroll
        for (int r = 0; r < 4; ++r) {
            const int pl = mh * 64 + i * 16 + q * 4 + r;
            const size_t px = (size_t)px0 + pl;
            float s = 0.0f, ssq = 0.0f;
            #pragma unroll
            for (int j = 0; j < 4; ++j) {
                const int col = nh * 64 + j * 16 + ln;
                float v = acc[i][j][r] + biasv[j] + bf2f(XLb[px * 256 + col]);
                acc[i][j][r] = v;
                s += v; ssq += v * v;
            }
            #pragma unroll
            for (int o = 1; o <= 8; o <<= 1) {
                s += __shfl_xor(s, o); ssq += __shfl_xor(ssq, o);
            }
            if (ln == 0) { part_s[nh][pl] = s; part_q[nh][pl] = ssq; }
        }
    }
    __syncthreads();

    float muv[4][4], rsv[4][4];
    #pragma unroll
    for (int i = 0; i < 4; ++i) {
        #pragma unroll
        for (int r = 0; r < 4; ++r) {
            const int pl = mh * 64 + i * 16 + q * 4 + r;
            const float s  = part_s[0][pl] + part_s[1][pl] + part_s[2][pl] + part_s[3][pl];
            const float sq = part_q[0][pl] + part_q[1][pl] + part_q[2][pl] + part_q[3][pl];
            const float mu = s * (1.0f / 256.0f);
            muv[i][r] = mu;
            rsv[i][r] = rsqrtf(sq * (1.0f / 256.0f) - mu * mu + 1e-5f);
        }
    }
    __syncthreads();   // done with sm.AB; reuse as sm.T

    // chunked transpose + NCHW write (chunk = 32 pixels)
    #pragma unroll
    for (int ck = 0; ck < 4; ++ck) {
        if (mh == (ck >> 1)) {
            const int ib = (ck & 1) * 2;
            #pragma unroll
            for (int ii = 0; ii < 2; ++ii) {
                const int i = ib + ii;
                #pragma unroll
                for (int j = 0; j < 4; ++j) {
                    const int col = nh * 64 + j * 16 + ln;
                    #pragma unroll
                    for (int r = 0; r < 4; ++r) {
                        sm.T[col * 33 + ii * 16 + q * 4 + r] =
                            (acc[i][j][r] - muv[i][r]) * rsv[i][r] * gv[j] + bvv[j];
                    }
                }
            }
        }
        __syncthreads();
        const int pxc = px0 + ck * 32;          // 32-aligned; 40000%32==0 so
        const int bb = pxc / HWSZ;              // no mid-chunk batch crossing
        const int hw0 = pxc - bb * HWSZ;
        #pragma unroll
        for (int p = 0; p < 16; ++p) {
            const int idx = t + p * 512;
            const int c = idx >> 5, pxl = idx & 31;
            Out[((size_t)(bb * 256 + c)) * HWSZ + hw0 + pxl] = sm.T[c * 33 + pxl];
        }
        __syncthreads();
    }
}

// ---------------------------------------------------------------------------
// 7x7 local-window attention via MFMA, NHWC bf16, replicate pad via clamp.
// (unchanged; XCD-contiguous swizzle kept)
// ---------------------------------------------------------------------------
__global__ __launch_bounds__(256) void attn_bf16(
    const unsigned short* Q, const unsigned short* __restrict__ K,
    const unsigned short* __restrict__ V, unsigned short* A)
{
    __shared__ __align__(16) unsigned short vt[32 * 536];   // 34304 B
    const int flat = blockIdx.x + 169 * (blockIdx.y + 8 * blockIdx.z);
    const int wsz = (flat & 7) * 338 + (flat >> 3);   // 2704/8 = 338
    const int tile = wsz >> 4, rem = wsz & 15;
    const int head = rem >> 1, b = rem & 1;
    const int tiy = tile / 13, tix = tile - tiy * 13;
    const int h0 = tiy * 16, w0 = tix * 16;
    const int t = threadIdx.x;
    const int lane = t & 63, wv = t >> 6;
    const int g = lane >> 4, n = lane & 15;
    const int co = head * 32;
    const size_t pxb = (size_t)b * HWSZ;

    for (int idx = t; idx < 832; idx += 256) {
        if (idx < 704) {
            int ch = idx / 22, r = idx - ch * 22;
            *(unsigned int*)&vt[ch * 536 + r * 24 + 22] = 0u;
        } else {
            int k2 = idx - 704;
            int ch = k2 >> 2, e = k2 & 3;
            *(unsigned int*)&vt[ch * 536 + 528 + e * 2] = 0u;
        }
    }
    for (int idx = t; idx < 484 * 4; idx += 256) {
        int pos = idx >> 2, chunk = idx & 3;
        int r = pos / 22, c = pos - r * 22;
        int gh = min(max(h0 + r - 3, 0), HH - 1);
        int gw = min(max(w0 + c - 3, 0), WW - 1);
        bf16x8 v8 = *(const bf16x8*)(V + (pxb + gh * WW + gw) * 256 + co + chunk * 8);
        unsigned short* dp = &vt[(chunk * 8) * 536 + r * 24 + c];
        #pragma unroll
        for (int e = 0; e < 8; ++e) dp[e * 536] = (unsigned short)v8[e];
    }
    __syncthreads();

    const f32x4 z4 = {0.f, 0.f, 0.f, 0.f};
    const int qw  = min(w0 + n, WW - 1);
    const int kc0 = min(max(w0 - 3 + n, 0), WW - 1);
    const int kc1 = min(w0 + 13 + n, WW - 1);
    const bool hi2 = (g >> 1) != 0;
    const int src0 = ((g & 1) * 2) * 16 + n;
    const int src1 = src0 + 16;

    for (int hh = 0; hh < 4; ++hh) {
        const int hl = wv * 4 + hh;
        const int h = h0 + hl;
        const int hc = min(h, HH - 1);

        const bf16x8 qf = *(const bf16x8*)(Q + (pxb + hc * WW + qw) * 256 + co + g * 8);

        f32x4 s0[7], s1[7];
        #pragma unroll
        for (int i = 0; i < 7; ++i) {
            const int gh = min(max(h - 3 + i, 0), HH - 1);
            const unsigned short* kr = K + (pxb + gh * WW) * 256 + co + g * 8;
            bf16x8 a0 = *(const bf16x8*)(kr + (size_t)kc0 * 256);
            bf16x8 a1 = *(const bf16x8*)(kr + (size_t)kc1 * 256);
            s0[i] = __builtin_amdgcn_mfma_f32_16x16x32_bf16(a0, qf, z4, 0, 0, 0);
            s1[i] = __builtin_amdgcn_mfma_f32_16x16x32_bf16(a1, qf, z4, 0, 0, 0);
        }

        float mx = -3.0e38f;
        #pragma unroll
        for (int r = 0; r < 4; ++r) {
            float m0 = s0[0][r], m1 = s1[0][r];
            #pragma unroll
            for (int i = 1; i < 7; ++i) {
                m0 = fmaxf(m0, s0[i][r]);
                m1 = fmaxf(m1, s1[i][r]);
            }
            const int k0 = 4 * g + r, k1 = k0 + 16;
            mx = fmaxf(mx, ((unsigned)(k0 - n) <= 6u) ? m0 : -3.0e38f);
            mx = fmaxf(mx, ((unsigned)(k1 - n) <= 6u) ? m1 : -3.0e38f);
        }
        mx = fmaxf(mx, __shfl_xor(mx, 16));
        mx = fmaxf(mx, __shfl_xor(mx, 32));

        float sum = 0.0f;
        #pragma unroll
        for (int r = 0; r < 4; ++r) {
            const int k0 = 4 * g + r, k1 = k0 + 16;
            const bool in0 = (unsigned)(k0 - n) <= 6u;
            const bool in1 = (unsigned)(k1 - n) <= 6u;
            #pragma unroll
            for (int i = 0; i < 7; ++i) {
                float e0 = in0 ? __expf((s0[i][r] - mx) * 0.17677669529663687f) : 0.0f;
                float e1 = in1 ? __expf((s1[i][r] - mx) * 0.17677669529663687f) : 0.0f;
                s0[i][r] = e0; s1[i][r] = e1;
                sum += e0 + e1;
            }
        }
        sum += __shfl_xor(sum, 16);
        sum += __shfl_xor(sum, 32);
        const float inv = __builtin_amdgcn_rcpf(sum);

        unsigned int pa[7], pb[7], pc[7], pd[7];
        #pragma unroll
        for (int i = 0; i < 7; ++i) {
            pa[i] = cvtpk_bf16(s0[i][0] * inv, s0[i][1] * inv);
            pb[i] = cvtpk_bf16(s0[i][2] * inv, s0[i][3] * inv);
            pc[i] = cvtpk_bf16(s1[i][0] * inv, s1[i][1] * inv);
            pd[i] = cvtpk_bf16(s1[i][2] * inv, s1[i][3] * inv);
        }

        f32x4 acc0 = z4, acc1 = z4;
        #pragma unroll
        for (int i = 0; i < 7; ++i) {
            const int a0s = __shfl((int)pa[i], src0);
            const int c0s = __shfl((int)pc[i], src0);
            const int b0s = __shfl((int)pb[i], src0);
            const int d0s = __shfl((int)pd[i], src0);
            const int a1s = __shfl((int)pa[i], src1);
            const int c1s = __shfl((int)pc[i], src1);
            const int b1s = __shfl((int)pb[i], src1);
            const int d1s = __shfl((int)pd[i], src1);
            union { unsigned int u[4]; bf16x8 v; } pu;
            pu.u[0] = (unsigned int)(hi2 ? c0s : a0s);
            pu.u[1] = (unsigned int)(hi2 ? d0s : b0s);
            pu.u[2] = (unsigned int)(hi2 ? c1s : a1s);
            pu.u[3] = (unsigned int)(hi2 ? d1s : b1s);
            const unsigned short* vr = &vt[(hl + i) * 24 + g * 8];
            bf16x8 vf0 = *(const bf16x8*)(vr + n * 536);
            bf16x8 vf1 = *(const bf16x8*)(vr + (n + 16) * 536);
            acc0 = __builtin_amdgcn_mfma_f32_16x16x32_bf16(pu.v, vf0, acc0, 0, 0, 0);
            acc1 = __builtin_amdgcn_mfma_f32_16x16x32_bf16(pu.v, vf1, acc1, 0, 0, 0);
        }

        if (h < HH) {
            unsigned short* ap = A + (pxb + h * WW) * 256 + co + n;
            const int wp = w0 + g * 4;
            #pragma unroll
            for (int r = 0; r < 4; ++r) {
                if (wp + r < WW) {
                    ap[(size_t)(wp + r) * 256]      = f2bf(acc0[r]);
                    ap[(size_t)(wp + r) * 256 + 16] = f2bf(acc1[r]);
                }
            }
        }
    }
}

// ---------------------------------------------------------------------------
// LN1: wave-per-pixel over contiguous 256 channels (NHWC fp32 in, bf16 out).
// ---------------------------------------------------------------------------
__global__ __launch_bounds__(256) void ln1_k(
    const float* __restrict__ X, const float* __restrict__ g,
    const float* __restrict__ bt, unsigned short* __restrict__ XLb)
{
    const int wv = threadIdx.x >> 6, lane = threadIdx.x & 63;
    const size_t px = (size_t)blockIdx.x * 4 + wv;
    const float4 v = *(const float4*)(X + px * 256 + lane * 4);
    float s = v.x + v.y + v.z + v.w;
    float ss = v.x * v.x + v.y * v.y + v.z * v.z + v.w * v.w;
    #pragma unroll
    for (int o = 32; o; o >>= 1) { s += __shfl_xor(s, o); ss += __shfl_xor(ss, o); }
    const float mu = s * (1.0f / 256.0f);
    const float var = ss * (1.0f / 256.0f) - mu * mu;
    const float rs = rsqrtf(var + 1e-5f);
    const float4 gv = *(const float4*)(g + lane * 4);
    const float4 bv = *(const float4*)(bt + lane * 4);
    ushort4 o4;
    o4.x = f2bf((v.x - mu) * rs * gv.x + bv.x);
    o4.y = f2bf((v.y - mu) * rs * gv.y + bv.y);
    o4.z = f2bf((v.z - mu) * rs * gv.z + bv.z);
    o4.w = f2bf((v.w - mu) * rs * gv.w + bv.w);
    *(ushort4*)(XLb + px * 256 + lane * 4) = o4;
}

// ---------------------------------------------------------------------------
// Workspace (bytes):                                      total 216.6 MB
//   0         : Fl_bf  [80000][64]  bf16   (10.24 MB)
//   10240000  : Fc_bf  [80000][256] bf16   (40.96)  ┐ after Wcat gemm this
//   51200000  : Qb/Ab  [80000][256] bf16   (40.96)  ├ whole 163.84 MB region
//   92160000  : Kb, Vb [2x 40.96]                   ┘ becomes Y1 [80000][1024]
//   174080000 : XLb    [80000][256] bf16   (40.96)
//   215040000 : bf16 weights (~1.5 MB)
//   d_out     : XW fp32 NHWC scratch (consumed by ln1), then final NCHW out
// ---------------------------------------------------------------------------
extern "C" void kernel_launch(void* const* d_in, const int* in_sizes, int n_in,
                              void* d_out, int out_size, void* d_ws, size_t ws_size,
                              hipStream_t stream)
{
    const float* F_lidar = (const float*)d_in[0];
    const float* F_cam   = (const float*)d_in[1];
    const float* Wq  = (const float*)d_in[2];
    const float* Wk  = (const float*)d_in[3];
    const float* Wv  = (const float*)d_in[4];
    const float* Wo  = (const float*)d_in[5];
    const float* Wr  = (const float*)d_in[6];
    const float* g1  = (const float*)d_in[7];
    const float* b1  = (const float*)d_in[8];
    const float* g2  = (const float*)d_in[9];
    const float* b2  = (const float*)d_in[10];
    const float* W1  = (const float*)d_in[11];
    const float* bf1 = (const float*)d_in[12];
    const float* W2  = (const float*)d_in[13];
    const float* bf2 = (const float*)d_in[14];

    char* wsb = (char*)d_ws;
    unsigned short* Fl  = (unsigned short*)(wsb);
    unsigned short* Fc  = (unsigned short*)(wsb + 10240000);
    unsigned short* Qb  = (unsigned short*)(wsb + 51200000);
    unsigned short* Kb  = (unsigned short*)(wsb + 92160000);
    unsigned short* Vb  = (unsigned short*)(wsb + 133120000);
    unsigned short* Y1b = Fc;                             // [80000][1024] bf16
    unsigned short* XLb = (unsigned short*)(wsb + 174080000);
    unsigned short* Wq_b = (unsigned short*)(wsb + 215040000);
    unsigned short* Wk_b = Wq_b + 16384;
    unsigned short* Wv_b = Wk_b + 65536;
    unsigned short* Wcat = Wv_b + 65536;
    unsigned short* W1t  = Wcat + 81920;
    unsigned short* W2t  = W1t + 262144;
    float* XW  = (float*)d_out;
    float* out = (float*)d_out;

    const dim3 blk(256);

    cvt_weights<<<dim3(1024, 6), blk, 0, stream>>>(Wq, Wk, Wv, Wo, Wr, W1, W2,
        Wq_b, Wk_b, Wv_b, Wcat, W1t, W2t);
    to_nhwc<<<dim3(625, 1, 2), blk, 0, stream>>>(F_lidar, Fl, 64);
    to_nhwc<<<dim3(625, 4, 2), blk, 0, stream>>>(F_cam, Fc, 256);

    // Q/K/V projections (bf16 out); flag 4 = XCD swizzle (A-panel reuse)
    gemm_bf16<<<dim3(625, 2), blk, 0, stream>>>(Fl, 64, Fl, 64, 64,
        Wq_b, 64, 64, Qb, nullptr, nullptr, 4, 256);
    gemm_bf16<<<dim3(625, 2), blk, 0, stream>>>(Fc, 256, Fc, 256, 256,
        Wk_b, 256, 256, Kb, nullptr, nullptr, 4, 256);
    gemm_bf16<<<dim3(625, 2), blk, 0, stream>>>(Fc, 256, Fc, 256, 256,
        Wv_b, 256, 256, Vb, nullptr, nullptr, 4, 256);

    // attention (A overwrites Q in-place; each block touches only its tile)
    attn_bf16<<<dim3(169, 8, 2), blk, 0, stream>>>(Qb, Kb, Vb, Qb);

    // fused out-proj + lidar residual: K=320 concat GEMM -> fp32 XW (d_out)
    gemm_bf16<<<dim3(625, 2), blk, 0, stream>>>(Qb, 256, Fl, 64, 256,
        Wcat, 320, 320, nullptr, XW, nullptr, 4, 256);

    // LN1 -> bf16 XLb
    ln1_k<<<dim3(20000), blk, 0, stream>>>(XW, g1, b1, XLb);

    // FFN half 1: full-width hidden, one dispatch (relu + bias), Y1 bf16
    gemm_bf16<<<dim3(625, 8), blk, 0, stream>>>(XLb, 256, XLb, 256, 256,
        W1t, 256, 256, Y1b, nullptr, bf1, 5, 1024);

    // FFN half 2 fused with residual + LN2 + NCHW write (no Y2 buffer)
    ffn2_ln2<<<dim3(625), dim3(512), 0, stream>>>(Y1b, XLb, W2t, bf2, g2, b2, out);
}

// Round 9
// 650.622 us; speedup vs baseline: 1.5865x; 1.0490x over previous
//
#include <hip/hip_runtime.h>
#include <stdint.h>

#define HH 200
#define WW 200
#define HWSZ 40000
#define NPX 80000

typedef __attribute__((ext_vector_type(8))) short bf16x8;
typedef __attribute__((ext_vector_type(4))) float f32x4;

#define VM_WAIT(N) asm volatile("s_waitcnt vmcnt(" #N ")" ::: "memory")
#define LGKM_WAIT0 asm volatile("s_waitcnt lgkmcnt(0)" ::: "memory")
#define BARRIER()  __builtin_amdgcn_s_barrier()
#define SCHED_FENCE() __builtin_amdgcn_sched_barrier(0)

__device__ __forceinline__ float bf2f(unsigned short u) {
    union { uint32_t i; float f; } c; c.i = ((uint32_t)u) << 16; return c.f;
}
__device__ __forceinline__ unsigned short f2bf(float f) {
    union { float f; uint32_t i; } c; c.f = f;
    uint32_t r = c.i + 0x7FFF + ((c.i >> 16) & 1);   // RNE
    return (unsigned short)(r >> 16);
}
__device__ __forceinline__ unsigned int cvtpk_bf16(float lo, float hi) {
    unsigned int r;
    asm("v_cvt_pk_bf16_f32 %0, %1, %2" : "=v"(r) : "v"(lo), "v"(hi));
    return r;
}
__device__ __forceinline__ void gload16(const void* g, void* l) {
    __builtin_amdgcn_global_load_lds(
        (const __attribute__((address_space(1))) unsigned int*)g,
        (__attribute__((address_space(3))) unsigned int*)l, 16, 0, 0);
}

// ---------------------------------------------------------------------------
// Weight conversion: fp32 -> bf16. Wkv = [Wk; Wv] rows (512 x 256);
// Wcat = concat(Wo, Wr) along k; W1/W2 transposed to [cout][cin].
// ---------------------------------------------------------------------------
__global__ __launch_bounds__(256) void cvt_weights(
    const float* __restrict__ Wq, const float* __restrict__ Wk,
    const float* __restrict__ Wv, const float* __restrict__ Wo,
    const float* __restrict__ Wr, const float* __restrict__ W1,
    const float* __restrict__ W2,
    unsigned short* Wq_b, unsigned short* Wkv_b,
    unsigned short* Wcat, unsigned short* W1t, unsigned short* W2t)
{
    const int seg = blockIdx.y;
    const int idx = blockIdx.x * 256 + threadIdx.x;
    if (seg == 0)      { if (idx < 16384) Wq_b[idx] = f2bf(Wq[idx]); }
    else if (seg == 1) {
        if (idx < 131072) {
            int r = idx >> 8, k = idx & 255;
            Wkv_b[idx] = f2bf(r < 256 ? Wk[r * 256 + k] : Wv[(r - 256) * 256 + k]);
        }
    } else if (seg == 2) {
        if (idx < 81920) {
            int r = idx / 320, k = idx - r * 320;
            Wcat[idx] = f2bf(k < 256 ? Wo[r * 256 + k] : Wr[r * 64 + (k - 256)]);
        }
    } else if (seg == 3) {
        if (idx < 262144) { int o = idx >> 8, i = idx & 255; W1t[idx] = f2bf(W1[i * 1024 + o]); }
    } else {
        if (idx < 262144) { int o = idx >> 10, i = idx & 1023; W2t[idx] = f2bf(W2[i * 256 + o]); }
    }
}

// ---------------------------------------------------------------------------
// NCHW fp32 -> NHWC bf16 (64px x 64c LDS tile).
// ---------------------------------------------------------------------------
__global__ __launch_bounds__(256) void to_nhwc(
    const float* __restrict__ src, unsigned short* __restrict__ dst, int C)
{
    __shared__ unsigned short T[64][72];
    const int b = blockIdx.z, c0 = blockIdx.y * 64, px0 = blockIdx.x * 64;
    const int t = threadIdx.x;
    const int pxl = t & 63, cl0 = t >> 6;
    const float* sp = src + ((size_t)(b * C + c0 + cl0)) * HWSZ + px0 + pxl;
    #pragma unroll
    for (int i = 0; i < 16; ++i)
        T[pxl][cl0 + i * 4] = f2bf(sp[(size_t)i * 4 * HWSZ]);
    __syncthreads();
    #pragma unroll
    for (int r = 0; r < 2; ++r) {
        int idx = t + r * 256;
        int p = idx >> 3, cof = (idx & 7) * 8;
        uint4 v = *(const uint4*)&T[p][cof];
        *(uint4*)(dst + ((size_t)(b * HWSZ + px0 + p)) * C + c0 + cof) = v;
    }
}

// ---------------------------------------------------------------------------
// bf16 MFMA GEMM, tile 128x128, BK=32, counted-vmcnt double buffer.
// flags: 1=relu, 2=fp32 accumulate, 4=XCD swizzle (y-fastest grouping),
// 8=split bf16 output at cout 256 (OutB / OutB2) for the fused K|V GEMM.
// ---------------------------------------------------------------------------
__global__ __launch_bounds__(256) void gemm_bf16(
    const unsigned short* __restrict__ In, int inStride,
    const unsigned short* __restrict__ In2, int in2Stride, int K1,
    const unsigned short* __restrict__ Wb, int wStride, int Ktot,
    unsigned short* __restrict__ OutB, unsigned short* __restrict__ OutB2,
    float* __restrict__ OutF,
    const float* __restrict__ bias, int flags, int outStride)
{
    __shared__ bf16x8 AB[2][1024];   // per buf: [0..511] A, [512..1023] B
    const int t = threadIdx.x;
    int bx = blockIdx.x, by = blockIdx.y;
    if (flags & 4) {
        const int nxy = gridDim.x * gridDim.y;
        const int flat = blockIdx.x + gridDim.x * blockIdx.y;
        const int qq = nxy >> 3, rr = nxy & 7;
        const int xcd = flat & 7, idx = flat >> 3;
        const int w2 = (xcd < rr ? xcd * (qq + 1)
                                 : rr * (qq + 1) + (xcd - rr) * qq) + idx;
        by = w2 % gridDim.y;
        bx = w2 / gridDim.y;
    }
    const int px0 = bx * 128;
    const int n0 = by * 128;
    const int lane = t & 63, w = t >> 6;
    const int mh = w & 1, nh = w >> 1;

    f32x4 acc[4][4] = {};

    auto STAGE = [&](int buf, int k0s) {   // 4 gload16 per thread
        #pragma unroll
        for (int r = 0; r < 2; ++r) {
            const int c = t + r * 256;
            const int l = c & 63;
            const int ko = k0s + ((l >> 4) << 3);
            const int mt = c >> 6;
            {
                const int px = px0 + mt * 16 + (l & 15);
                const unsigned short* sp = (ko < K1)
                    ? (In  + (size_t)px * inStride  + ko)
                    : (In2 + (size_t)px * in2Stride + (ko - K1));
                gload16(sp, &AB[buf][c]);
            }
            {
                const int cc = n0 + mt * 16 + (l & 15);
                gload16(Wb + (size_t)cc * wStride + ko, &AB[buf][512 + c]);
            }
        }
    };

    const int nsteps = Ktot >> 5;
    STAGE(0, 0);
    if (nsteps > 1) STAGE(1, 32);
    int cur = 0;

    for (int s = 0; s < nsteps - 1; ++s) {
        VM_WAIT(4);
        BARRIER();
        bf16x8 av[4], bv[4];
        #pragma unroll
        for (int i = 0; i < 4; ++i) av[i] = AB[cur][(mh * 4 + i) * 64 + lane];
        #pragma unroll
        for (int j = 0; j < 4; ++j) bv[j] = AB[cur][512 + (nh * 4 + j) * 64 + lane];
        LGKM_WAIT0;
        BARRIER();
        SCHED_FENCE();
        if (s + 2 < nsteps) STAGE(cur, (s + 2) * 32);
        #pragma unroll
        for (int i = 0; i < 4; ++i)
            #pragma unroll
            for (int j = 0; j < 4; ++j)
                acc[i][j] = __builtin_amdgcn_mfma_f32_16x16x32_bf16(
                    av[i], bv[j], acc[i][j], 0, 0, 0);
        cur ^= 1;
    }
    VM_WAIT(0);
    BARRIER();
    {
        bf16x8 av[4], bv[4];
        #pragma unroll
        for (int i = 0; i < 4; ++i) av[i] = AB[cur][(mh * 4 + i) * 64 + lane];
        #pragma unroll
        for (int j = 0; j < 4; ++j) bv[j] = AB[cur][512 + (nh * 4 + j) * 64 + lane];
        #pragma unroll
        for (int i = 0; i < 4; ++i)
            #pragma unroll
            for (int j = 0; j < 4; ++j)
                acc[i][j] = __builtin_amdgcn_mfma_f32_16x16x32_bf16(
                    av[i], bv[j], acc[i][j], 0, 0, 0);
    }

    const int q = lane >> 4, ln = lane & 15;
    const bool relu = (flags & 1) != 0, accum = (flags & 2) != 0;
    const bool split = (flags & 8) != 0;
    #pragma unroll
    for (int i = 0; i < 4; ++i) {
        #pragma unroll
        for (int j = 0; j < 4; ++j) {
            const int coutv = n0 + nh * 64 + j * 16 + ln;
            const float bval = bias ? bias[coutv] : 0.0f;
            #pragma unroll
            for (int r = 0; r < 4; ++r) {
                const int px = px0 + mh * 64 + i * 16 + q * 4 + r;
                float v = acc[i][j][r] + bval;
                if (relu) v = fmaxf(v, 0.0f);
                if (OutB) {
                    if (split && coutv >= 256)
                        OutB2[(size_t)px * outStride + coutv - 256] = f2bf(v);
                    else
                        OutB[(size_t)px * outStride + coutv] = f2bf(v);
                } else {
                    float* op = OutF + (size_t)px * 256 + coutv;
                    if (accum) v += *op;
                    *op = v;
                }
            }
        }
    }
}

// ---------------------------------------------------------------------------
// Fused out-proj + lidar residual + LN1: XLb = LN(concat(A,Fl) x Wcat^T).
// Block = 512 thr, tile 128px x 256 cout (full rows), K=320 (10 steps).
// Same counted-vmcnt template as ffn2_ln2; epilogue: per-pixel LN stats
// (16-lane shfl + 4-way nh partials) then direct NHWC bf16 write of XLb.
// Eliminates the ln1 dispatch + the fp32 XW round-trip through d_out.
// ---------------------------------------------------------------------------
__global__ __launch_bounds__(512) void proj_ln1(
    const unsigned short* __restrict__ Aq,   // [NPX][256] bf16 (attn out)
    const unsigned short* __restrict__ Fl,   // [NPX][64]  bf16 (lidar)
    const unsigned short* __restrict__ Wcat, // [256][320] bf16
    const float* __restrict__ g1, const float* __restrict__ b1,
    unsigned short* __restrict__ XLb)        // [NPX][256] bf16
{
    __shared__ bf16x8 AB[2][1536];           // 48 KB
    __shared__ float part_s[4][128], part_q[4][128];

    const int t = threadIdx.x;
    const int px0 = blockIdx.x * 128;
    const int lane = t & 63, w = t >> 6;
    const int mh = w & 1, nh = w >> 1;
    const int q = lane >> 4, ln = lane & 15;

    float gv[4], bvv[4];
    #pragma unroll
    for (int j = 0; j < 4; ++j) {
        const int col = nh * 64 + j * 16 + ln;
        gv[j] = g1[col];
        bvv[j] = b1[col];
    }

    f32x4 acc[4][4] = {};

    auto STAGE = [&](int buf, int k0s) {   // 3 gload16 per thread
        #pragma unroll
        for (int r = 0; r < 3; ++r) {
            const int c = t + r * 512;
            const int l = c & 63;
            const int ko = k0s + ((l >> 4) << 3);
            if (c < 512) {                       // A frags (concat)
                const int mt = c >> 6;
                const int px = px0 + mt * 16 + (l & 15);
                const unsigned short* sp = (ko < 256)
                    ? (Aq + (size_t)px * 256 + ko)
                    : (Fl + (size_t)px * 64 + (ko - 256));
                gload16(sp, &AB[buf][c]);
            } else {                             // B frags: 16 n-tiles
                const int c2 = c - 512;
                const int nt = c2 >> 6;
                const int cc = nt * 16 + (l & 15);
                gload16(Wcat + (size_t)cc * 320 + ko, &AB[buf][c]);
            }
        }
    };

    STAGE(0, 0);
    STAGE(1, 32);
    int cur = 0;

    for (int s = 0; s < 9; ++s) {
        VM_WAIT(3);
        BARRIER();
        bf16x8 av[4], bv[4];
        #pragma unroll
        for (int i = 0; i < 4; ++i) av[i] = AB[cur][(mh * 4 + i) * 64 + lane];
        #pragma unroll
        for (int j = 0; j < 4; ++j) bv[j] = AB[cur][512 + (nh * 4 + j) * 64 + lane];
        LGKM_WAIT0;
        BARRIER();
        SCHED_FENCE();
        if (s + 2 < 10) STAGE(cur, (s + 2) * 32);
        #pragma unroll
        for (int i = 0; i < 4; ++i)
            #pragma unroll
            for (int j = 0; j < 4; ++j)
                acc[i][j] = __builtin_amdgcn_mfma_f32_16x16x32_bf16(
                    av[i], bv[j], acc[i][j], 0, 0, 0);
        cur ^= 1;
    }
    VM_WAIT(0);
    BARRIER();
    {
        bf16x8 av[4], bv[4];
        #pragma unroll
        for (int i = 0; i < 4; ++i) av[i] = AB[cur][(mh * 4 + i) * 64 + lane];
        #pragma unroll
        for (int j = 0; j < 4; ++j) bv[j] = AB[cur][512 + (nh * 4 + j) * 64 + lane];
        #pragma unroll
        for (int i = 0; i < 4; ++i)
            #pragma unroll
            for (int j = 0; j < 4; ++j)
                acc[i][j] = __builtin_amdgcn_mfma_f32_16x16x32_bf16(
                    av[i], bv[j], acc[i][j], 0, 0, 0);
    }

    // per-pixel LN stats
    #pragma unroll
    for (int i = 0; i < 4; ++i) {
        #pragma unroll
        for (int r = 0; r < 4; ++r) {
            const int pl = mh * 64 + i * 16 + q * 4 + r;
            float s = 0.0f, ssq = 0.0f;
            #pragma unroll
            for (int j = 0; j < 4; ++j) {
                const float v = acc[i][j][r];
                s += v; ssq += v * v;
            }
            #pragma unroll
            for (int o = 1; o <= 8; o <<= 1) {
                s += __shfl_xor(s, o); ssq += __shfl_xor(ssq, o);
            }
            if (ln == 0) { part_s[nh][pl] = s; part_q[nh][pl] = ssq; }
        }
    }
    __syncthreads();

    #pragma unroll
    for (int i = 0; i < 4; ++i) {
        #pragma unroll
        for (int r = 0; r < 4; ++r) {
            const int pl = mh * 64 + i * 16 + q * 4 + r;
            const size_t px = (size_t)px0 + pl;
            const float s  = part_s[0][pl] + part_s[1][pl] + part_s[2][pl] + part_s[3][pl];
            const float sq = part_q[0][pl] + part_q[1][pl] + part_q[2][pl] + part_q[3][pl];
            const float mu = s * (1.0f / 256.0f);
            const float rs = rsqrtf(sq * (1.0f / 256.0f) - mu * mu + 1e-5f);
            #pragma unroll
            for (int j = 0; j < 4; ++j) {
                const int col = nh * 64 + j * 16 + ln;
                XLb[px * 256 + col] = f2bf((acc[i][j][r] - mu) * rs * gv[j] + bvv[j]);
            }
        }
    }
}

// ---------------------------------------------------------------------------
// Fused FFN-2nd-half + LN2: Out = LN(XLb + Y1*W2t + bf2) -> NCHW fp32.
// (unchanged this round)
// ---------------------------------------------------------------------------
__global__ __launch_bounds__(512) void ffn2_ln2(
    const unsigned short* __restrict__ Y1,
    const unsigned short* __restrict__ XLb,
    const unsigned short* __restrict__ W2t,
    const float* __restrict__ bf2v,
    const float* __restrict__ g2, const float* __restrict__ b2,
    float* __restrict__ Out)
{
    __shared__ union {
        bf16x8 AB[2][1536];
        float  T[256 * 33];
    } sm;
    __shared__ float part_s[4][128], part_q[4][128];

    const int t = threadIdx.x;
    const int px0 = blockIdx.x * 128;
    const int lane = t & 63, w = t >> 6;
    const int mh = w & 1, nh = w >> 1;
    const int q = lane >> 4, ln = lane & 15;

    float biasv[4], gv[4], bvv[4];
    #pragma unroll
    for (int j = 0; j < 4; ++j) {
        const int col = nh * 64 + j * 16 + ln;
        biasv[j] = bf2v[col];
        gv[j] = g2[col];
        bvv[j] = b2[col];
    }

    f32x4 acc[4][4] = {};

    auto STAGE = [&](int buf, int k0s) {
        #pragma unroll
        for (int r = 0; r < 3; ++r) {
            const int c = t + r * 512;
            const int l = c & 63;
            const int ko = k0s + ((l >> 4) << 3);
            if (c < 512) {
                const int mt = c >> 6;
                const int px = px0 + mt * 16 + (l & 15);
                gload16(Y1 + (size_t)px * 1024 + ko, &sm.AB[buf][c]);
            } else {
                const int c2 = c - 512;
                const int nt = c2 >> 6;
                const int cc = nt * 16 + (l & 15);
                gload16(W2t + (size_t)cc * 1024 + ko, &sm.AB[buf][c]);
            }
        }
    };

    STAGE(0, 0);
    STAGE(1, 32);
    int cur = 0;

    for (int s = 0; s < 31; ++s) {
        VM_WAIT(3);
        BARRIER();
        bf16x8 av[4], bv[4];
        #pragma unroll
        for (int i = 0; i < 4; ++i) av[i] = sm.AB[cur][(mh * 4 + i) * 64 + lane];
        #pragma unroll
        for (int j = 0; j < 4; ++j) bv[j] = sm.AB[cur][512 + (nh * 4 + j) * 64 + lane];
        LGKM_WAIT0;
        BARRIER();
        SCHED_FENCE();
        if (s + 2 < 32) STAGE(cur, (s + 2) * 32);
        #pragma unroll
        for (int i = 0; i < 4; ++i)
            #pragma unroll
            for (int j = 0; j < 4; ++j)
                acc[i][j] = __builtin_amdgcn_mfma_f32_16x16x32_bf16(
                    av[i], bv[j], acc[i][j], 0, 0, 0);
        cur ^= 1;
    }
    VM_WAIT(0);
    BARRIER();
    {
        bf16x8 av[4], bv[4];
        #pragma unroll
        for (int i = 0; i < 4; ++i) av[i] = sm.AB[cur][(mh * 4 + i) * 64 + lane];
        #pragma unroll
        for (int j = 0; j < 4; ++j) bv[j] = sm.AB[cur][512 + (nh * 4 + j) * 64 + lane];
        #pragma unroll
        for (int i = 0; i < 4; ++i)
            #pragma unroll
            for (int j = 0; j < 4; ++j)
                acc[i][j] = __builtin_amdgcn_mfma_f32_16x16x32_bf16(
                    av[i], bv[j], acc[i][j], 0, 0, 0);
    }

    #pragma unroll
    for (int i = 0; i < 4; ++i) {
        #pragma unroll
        for (int r = 0; r < 4; ++r) {
            const int pl = mh * 64 + i * 16 + q * 4 + r;
            const size_t px = (size_t)px0 + pl;
            float s = 0.0f, ssq = 0.0f;
            #pragma unroll
            for (int j = 0; j < 4; ++j) {
                const int col = nh * 64 + j * 16 + ln;
                float v = acc[i][j][r] + biasv[j] + bf2f(XLb[px * 256 + col]);
                acc[i][j][r] = v;
                s += v; ssq += v * v;
            }
            #pragma unroll
            for (int o = 1; o <= 8; o <<= 1) {
                s += __shfl_xor(s, o); ssq += __shfl_xor(ssq, o);
            }
            if (ln == 0) { part_s[nh][pl] = s; part_q[nh][pl] = ssq; }
        }
    }
    __syncthreads();

    float muv[4][4], rsv[4][4];
    #pragma unroll
    for (int i = 0; i < 4; ++i) {
        #pragma unroll
        for (int r = 0; r < 4; ++r) {
            const int pl = mh * 64 + i * 16 + q * 4 + r;
            const float s  = part_s[0][pl] + part_s[1][pl] + part_s[2][pl] + part_s[3][pl];
            const float sq = part_q[0][pl] + part_q[1][pl] + part_q[2][pl] + part_q[3][pl];
            const float mu = s * (1.0f / 256.0f);
            muv[i][r] = mu;
            rsv[i][r] = rsqrtf(sq * (1.0f / 256.0f) - mu * mu + 1e-5f);
        }
    }
    __syncthreads();

    #pragma unroll
    for (int ck = 0; ck < 4; ++ck) {
        if (mh == (ck >> 1)) {
            const int ib = (ck & 1) * 2;
            #pragma unroll
            for (int ii = 0; ii < 2; ++ii) {
                const int i = ib + ii;
                #pragma unroll
                for (int j = 0; j < 4; ++j) {
                    const int col = nh * 64 + j * 16 + ln;
                    #pragma unroll
                    for (int r = 0; r < 4; ++r) {
                        sm.T[col * 33 + ii * 16 + q * 4 + r] =
                            (acc[i][j][r] - muv[i][r]) * rsv[i][r] * gv[j] + bvv[j];
                    }
                }
            }
        }
        __syncthreads();
        const int pxc = px0 + ck * 32;
        const int bb = pxc / HWSZ;
        const int hw0 = pxc - bb * HWSZ;
        #pragma unroll
        for (int p = 0; p < 16; ++p) {
            const int idx = t + p * 512;
            const int c = idx >> 5, pxl = idx & 31;
            Out[((size_t)(bb * 256 + c)) * HWSZ + hw0 + pxl] = sm.T[c * 33 + pxl];
        }
        __syncthreads();
    }
}

// ---------------------------------------------------------------------------
// 7x7 local-window attention via MFMA (unchanged; XCD swizzle kept).
// ---------------------------------------------------------------------------
__global__ __launch_bounds__(256) void attn_bf16(
    const unsigned short* Q, const unsigned short* __restrict__ K,
    const unsigned short* __restrict__ V, unsigned short* A)
{
    __shared__ __align__(16) unsigned short vt[32 * 536];   // 34304 B
    const int flat = blockIdx.x + 169 * (blockIdx.y + 8 * blockIdx.z);
    const int wsz = (flat & 7) * 338 + (flat >> 3);
    const int tile = wsz >> 4, rem = wsz & 15;
    const int head = rem >> 1, b = rem & 1;
    const int tiy = tile / 13, tix = tile - tiy * 13;
    const int h0 = tiy * 16, w0 = tix * 16;
    const int t = threadIdx.x;
    const int lane = t & 63, wv = t >> 6;
    const int g = lane >> 4, n = lane & 15;
    const int co = head * 32;
    const size_t pxb = (size_t)b * HWSZ;

    for (int idx = t; idx < 832; idx += 256) {
        if (idx < 704) {
            int ch = idx / 22, r = idx - ch * 22;
            *(unsigned int*)&vt[ch * 536 + r * 24 + 22] = 0u;
        } else {
            int k2 = idx - 704;
            int ch = k2 >> 2, e = k2 & 3;
            *(unsigned int*)&vt[ch * 536 + 528 + e * 2] = 0u;
        }
    }
    for (int idx = t; idx < 484 * 4; idx += 256) {
        int pos = idx >> 2, chunk = idx & 3;
        int r = pos / 22, c = pos - r * 22;
        int gh = min(max(h0 + r - 3, 0), HH - 1);
        int gw = min(max(w0 + c - 3, 0), WW - 1);
        bf16x8 v8 = *(const bf16x8*)(V + (pxb + gh * WW + gw) * 256 + co + chunk * 8);
        unsigned short* dp = &vt[(chunk * 8) * 536 + r * 24 + c];
        #pragma unroll
        for (int e = 0; e < 8; ++e) dp[e * 536] = (unsigned short)v8[e];
    }
    __syncthreads();

    const f32x4 z4 = {0.f, 0.f, 0.f, 0.f};
    const int qw  = min(w0 + n, WW - 1);
    const int kc0 = min(max(w0 - 3 + n, 0), WW - 1);
    const int kc1 = min(w0 + 13 + n, WW - 1);
    const bool hi2 = (g >> 1) != 0;
    const int src0 = ((g & 1) * 2) * 16 + n;
    const int src1 = src0 + 16;

    for (int hh = 0; hh < 4; ++hh) {
        const int hl = wv * 4 + hh;
        const int h = h0 + hl;
        const int hc = min(h, HH - 1);

        const bf16x8 qf = *(const bf16x8*)(Q + (pxb + hc * WW + qw) * 256 + co + g * 8);

        f32x4 s0[7], s1[7];
        #pragma unroll
        for (int i = 0; i < 7; ++i) {
            const int gh = min(max(h - 3 + i, 0), HH - 1);
            const unsigned short* kr = K + (pxb + gh * WW) * 256 + co + g * 8;
            bf16x8 a0 = *(const bf16x8*)(kr + (size_t)kc0 * 256);
            bf16x8 a1 = *(const bf16x8*)(kr + (size_t)kc1 * 256);
            s0[i] = __builtin_amdgcn_mfma_f32_16x16x32_bf16(a0, qf, z4, 0, 0, 0);
            s1[i] = __builtin_amdgcn_mfma_f32_16x16x32_bf16(a1, qf, z4, 0, 0, 0);
        }

        float mx = -3.0e38f;
        #pragma unroll
        for (int r = 0; r < 4; ++r) {
            float m0 = s0[0][r], m1 = s1[0][r];
            #pragma unroll
            for (int i = 1; i < 7; ++i) {
                m0 = fmaxf(m0, s0[i][r]);
                m1 = fmaxf(m1, s1[i][r]);
            }
            const int k0 = 4 * g + r, k1 = k0 + 16;
            mx = fmaxf(mx, ((unsigned)(k0 - n) <= 6u) ? m0 : -3.0e38f);
            mx = fmaxf(mx, ((unsigned)(k1 - n) <= 6u) ? m1 : -3.0e38f);
        }
        mx = fmaxf(mx, __shfl_xor(mx, 16));
        mx = fmaxf(mx, __shfl_xor(mx, 32));

        float sum = 0.0f;
        #pragma unroll
        for (int r = 0; r < 4; ++r) {
            const int k0 = 4 * g + r, k1 = k0 + 16;
            const bool in0 = (unsigned)(k0 - n) <= 6u;
            const bool in1 = (unsigned)(k1 - n) <= 6u;
            #pragma unroll
            for (int i = 0; i < 7; ++i) {
                float e0 = in0 ? __expf((s0[i][r] - mx) * 0.17677669529663687f) : 0.0f;
                float e1 = in1 ? __expf((s1[i][r] - mx) * 0.17677669529663687f) : 0.0f;
                s0[i][r] = e0; s1[i][r] = e1;
                sum += e0 + e1;
            }
        }
        sum += __shfl_xor(sum, 16);
        sum += __shfl_xor(sum, 32);
        const float inv = __builtin_amdgcn_rcpf(sum);

        unsigned int pa[7], pb[7], pc[7], pd[7];
        #pragma unroll
        for (int i = 0; i < 7; ++i) {
            pa[i] = cvtpk_bf16(s0[i][0] * inv, s0[i][1] * inv);
            pb[i] = cvtpk_bf16(s0[i][2] * inv, s0[i][3] * inv);
            pc[i] = cvtpk_bf16(s1[i][0] * inv, s1[i][1] * inv);
            pd[i] = cvtpk_bf16(s1[i][2] * inv, s1[i][3] * inv);
        }

        f32x4 acc0 = z4, acc1 = z4;
        #pragma unroll
        for (int i = 0; i < 7; ++i) {
            const int a0s = __shfl((int)pa[i], src0);
            const int c0s = __shfl((int)pc[i], src0);
            const int b0s = __shfl((int)pb[i], src0);
            const int d0s = __shfl((int)pd[i], src0);
            const int a1s = __shfl((int)pa[i], src1);
            const int c1s = __shfl((int)pc[i], src1);
            const int b1s = __shfl((int)pb[i], src1);
            const int d1s = __shfl((int)pd[i], src1);
            union { unsigned int u[4]; bf16x8 v; } pu;
            pu.u[0] = (unsigned int)(hi2 ? c0s : a0s);
            pu.u[1] = (unsigned int)(hi2 ? d0s : b0s);
            pu.u[2] = (unsigned int)(hi2 ? c1s : a1s);
            pu.u[3] = (unsigned int)(hi2 ? d1s : b1s);
            const unsigned short* vr = &vt[(hl + i) * 24 + g * 8];
            bf16x8 vf0 = *(const bf16x8*)(vr + n * 536);
            bf16x8 vf1 = *(const bf16x8*)(vr + (n + 16) * 536);
            acc0 = __builtin_amdgcn_mfma_f32_16x16x32_bf16(pu.v, vf0, acc0, 0, 0, 0);
            acc1 = __builtin_amdgcn_mfma_f32_16x16x32_bf16(pu.v, vf1, acc1, 0, 0, 0);
        }

        if (h < HH) {
            unsigned short* ap = A + (pxb + h * WW) * 256 + co + n;
            const int wp = w0 + g * 4;
            #pragma unroll
            for (int r = 0; r < 4; ++r) {
                if (wp + r < WW) {
                    ap[(size_t)(wp + r) * 256]      = f2bf(acc0[r]);
                    ap[(size_t)(wp + r) * 256 + 16] = f2bf(acc1[r]);
                }
            }
        }
    }
}

// ---------------------------------------------------------------------------
// Workspace (bytes):                                      total 216.6 MB
//   0         : Fl_bf  [80000][64]  bf16   (10.24 MB)
//   10240000  : Fc_bf  [80000][256] bf16   (40.96)  ┐ after proj_ln1 this
//   51200000  : Qb/Ab  [80000][256] bf16   (40.96)  ├ whole 163.84 MB region
//   92160000  : Kb, Vb [2x 40.96]                   ┘ becomes Y1 [80000][1024]
//   174080000 : XLb    [80000][256] bf16   (40.96)
//   215040000 : bf16 weights (~1.5 MB): Wq(16K) Wkv(128K) Wcat(80K) W1t W2t
//   d_out     : final NCHW output only (no scratch use)
// ---------------------------------------------------------------------------
extern "C" void kernel_launch(void* const* d_in, const int* in_sizes, int n_in,
                              void* d_out, int out_size, void* d_ws, size_t ws_size,
                              hipStream_t stream)
{
    const float* F_lidar = (const float*)d_in[0];
    const float* F_cam   = (const float*)d_in[1];
    const float* Wq  = (const float*)d_in[2];
    const float* Wk  = (const float*)d_in[3];
    const float* Wv  = (const float*)d_in[4];
    const float* Wo  = (const float*)d_in[5];
    const float* Wr  = (const float*)d_in[6];
    const float* g1  = (const float*)d_in[7];
    const float* b1  = (const float*)d_in[8];
    const float* g2  = (const float*)d_in[9];
    const float* b2  = (const float*)d_in[10];
    const float* W1  = (const float*)d_in[11];
    const float* bf1 = (const float*)d_in[12];
    const float* W2  = (const float*)d_in[13];
    const float* bf2 = (const float*)d_in[14];

    char* wsb = (char*)d_ws;
    unsigned short* Fl  = (unsigned short*)(wsb);
    unsigned short* Fc  = (unsigned short*)(wsb + 10240000);
    unsigned short* Qb  = (unsigned short*)(wsb + 51200000);
    unsigned short* Kb  = (unsigned short*)(wsb + 92160000);
    unsigned short* Vb  = (unsigned short*)(wsb + 133120000);
    unsigned short* Y1b = Fc;                             // [80000][1024] bf16
    unsigned short* XLb = (unsigned short*)(wsb + 174080000);
    unsigned short* Wq_b  = (unsigned short*)(wsb + 215040000);
    unsigned short* Wkv_b = Wq_b + 16384;
    unsigned short* Wcat  = Wkv_b + 131072;
    unsigned short* W1t   = Wcat + 81920;
    unsigned short* W2t   = W1t + 262144;
    float* out = (float*)d_out;

    const dim3 blk(256);

    cvt_weights<<<dim3(1024, 5), blk, 0, stream>>>(Wq, Wk, Wv, Wo, Wr, W1, W2,
        Wq_b, Wkv_b, Wcat, W1t, W2t);
    to_nhwc<<<dim3(625, 1, 2), blk, 0, stream>>>(F_lidar, Fl, 64);
    to_nhwc<<<dim3(625, 4, 2), blk, 0, stream>>>(F_cam, Fc, 256);

    // Q projection
    gemm_bf16<<<dim3(625, 2), blk, 0, stream>>>(Fl, 64, Fl, 64, 64,
        Wq_b, 64, 64, Qb, nullptr, nullptr, nullptr, 4, 256);
    // fused K|V projection: N=512, split output at cout 256
    gemm_bf16<<<dim3(625, 4), blk, 0, stream>>>(Fc, 256, Fc, 256, 256,
        Wkv_b, 256, 256, Kb, Vb, nullptr, nullptr, 4 | 8, 256);

    // attention (A overwrites Q in-place)
    attn_bf16<<<dim3(169, 8, 2), blk, 0, stream>>>(Qb, Kb, Vb, Qb);

    // fused out-proj + residual + LN1 -> XLb (bf16 NHWC)
    proj_ln1<<<dim3(625), dim3(512), 0, stream>>>(Qb, Fl, Wcat, g1, b1, XLb);

    // FFN half 1: full-width hidden, one dispatch (relu + bias), Y1 bf16
    gemm_bf16<<<dim3(625, 8), blk, 0, stream>>>(XLb, 256, XLb, 256, 256,
        W1t, 256, 256, Y1b, nullptr, nullptr, bf1, 5, 1024);

    // FFN half 2 fused with residual + LN2 + NCHW write
    ffn2_ln2<<<dim3(625), dim3(512), 0, stream>>>(Y1b, XLb, W2t, bf2, g2, b2, out);
}